// Round 8
// baseline (1936.328 us; speedup 1.0000x reference)
//
#include <hip/hip_runtime.h>

// TrajectoryAttention on MI355X (gfx950), chunked pipeline, dtype-adaptive.
// R16: (1) landmarks single-RTT barrier: each block's slot carries candidate +
//   inv-norm + the FULL 64-float candidate column, every u64 word self-tagged
//   with the step (no store-ordering needed; parity double-buffer as R10).
//   Poller reads all 8 columns speculatively during the poll -> winner column
//   already in registers (cndmask select), curD = vf * invW (R9-proven form,
//   R9-proven quad-split norm order). Deletes per-step qT gather + f64
//   butterfly + sqrt/div; drops s_sleep. (2) workspace re-layout: weights/lm/
//   x1b/ob/k1b fixed (~43MB); everything else overlays one scratch region;
//   attn2 writes wc IN PLACE of g -> 92KB/Nc (was 129); floor ~85MB ->
//   Nc >= 392 guaranteed, chunk dispatch count halves.
// R15 (kept): reassociated attention (no 237-GFLOP xo@Wpkv GEMM).
// R14 (kept): 8 blocks/head co-located per XCD; qselT 128x64 tile.
// R13 (kept): gemm staging via global_load_lds + both-sides XOR swizzle.
// R12 (kept): all GEMM operands pre-converted bf16 [n][k]; x1b transposed.
// R11 (kept): landmarks qT slice in registers. R10: tagged packed-u64 sync.
// R9: 8 blocks/head f64 dots. R8: transposed qT. R7: threefry idx0.

using u16 = unsigned short;
using u32 = unsigned int;
using u64 = unsigned long long;

typedef short bf16x8 __attribute__((ext_vector_type(8)));
typedef float f32x4 __attribute__((ext_vector_type(4)));

#define N_ 3136
#define C_ 768
#define H_ 12
#define F_ 16
#define P_ 196
#define L_ 128
#define SC_ 0.35355339059327373f   // 64^-0.25
#define OUTPART_ ((size_t)2 * N_ * C_)
#define KB_ 8                      // blocks per head in landmarks
#define RPB_ 392                   // rows per block (3136/8)
#define SLOTW_ 80                  // u64 words per (parity,kb) slot

__device__ __forceinline__ float b2f(u16 u) {
  u32 x = ((u32)u) << 16; float f; __builtin_memcpy(&f, &x, 4); return f;
}
__device__ __forceinline__ float lo16f(u32 u) {
  u32 x = u << 16; float f; __builtin_memcpy(&f, &x, 4); return f;
}
__device__ __forceinline__ float hi16f(u32 u) {
  u32 x = u & 0xFFFF0000u; float f; __builtin_memcpy(&f, &x, 4); return f;
}
__device__ __forceinline__ u16 f2b(float f) {
  u32 u; __builtin_memcpy(&u, &f, 4);
  u32 r = (u + 0x7FFFu + ((u >> 16) & 1u)) >> 16;
  return (u16)r;
}
__device__ __forceinline__ u64 d2u(double d) { u64 u; __builtin_memcpy(&u, &d, 8); return u; }
__device__ __forceinline__ double u2d(u64 u) { double d; __builtin_memcpy(&d, &u, 8); return d; }

// direct global->LDS DMA, 16B per lane; lds base must be wave-uniform.
__device__ __forceinline__ void gll16(const void* g, void* l) {
  __builtin_amdgcn_global_load_lds(
      (__attribute__((address_space(1))) void*)g,
      (__attribute__((address_space(3))) void*)l, 16, 0, 0);
}

// dtype sniffer (bf16 vs f32 inputs) — votes f32 on this dataset (proven R4)
__global__ void detect_k(const u32* __restrict__ w, int* __restrict__ flag) {
  const int t = threadIdx.x;  // 64
  int hits = 0;
  #pragma unroll
  for (int i = 0; i < 16; ++i) {
    u32 word = w[t * 16 + i];
    u32 e = (word >> 7) & 0xFFu;
    if (e >= 110u && e <= 126u) hits++;
  }
  #pragma unroll
  for (int off = 32; off > 0; off >>= 1) hits += __shfl_down(hits, off);
  if (t == 0) flag[0] = (hits >= 512) ? 0 : 1;  // 0=bf16, 1=f32
}

// zero candidate slots: 24 heads x 2 parity x 8 blocks x SLOTW_ = 30720 u64.
__global__ void zcnt_k(u64* __restrict__ p) { p[blockIdx.x * 512 + threadIdx.x] = 0ull; }

// ---- exact JAX threefry2x32-20 core ----
__device__ __forceinline__ void tf2(u32 k0, u32 k1v, u32 c0, u32 c1, u32& o0, u32& o1) {
  u32 ks[3] = {k0, k1v, k0 ^ k1v ^ 0x1BD11BDAu};
  u32 x0 = c0 + ks[0], x1 = c1 + ks[1];
  const u32 rA[4] = {13u, 15u, 26u, 6u}, rB[4] = {17u, 29u, 16u, 24u};
  #pragma unroll
  for (int r = 0; r < 5; ++r) {
    #pragma unroll
    for (int q = 0; q < 4; ++q) {
      u32 rot = (r & 1) ? rB[q] : rA[q];
      x0 += x1; x1 = (x1 << rot) | (x1 >> (32u - rot)); x1 ^= x0;
    }
    x0 += ks[(r + 1) % 3];
    x1 += ks[(r + 2) % 3] + (u32)(r + 1);
  }
  o0 = x0; o1 = x1;
}

// jax.random.randint(key(42), (24,), 0, 3136), partitionable — PROVEN (R7).
__device__ __forceinline__ int tf_idx0(int bh) {
  u32 a0, a1, b0, b1;
  tf2(0u, 42u, 0u, 0u, a0, a1);
  tf2(0u, 42u, 0u, 1u, b0, b1);
  u32 j = (u32)bh;
  u32 h0, h1, l0, l1;
  tf2(a0, a1, 0u, j, h0, h1);
  u32 hi = h0 ^ h1;
  tf2(b0, b1, 0u, j, l0, l1);
  u32 lo = l0 ^ l1;
  return (int)(((hi % 3136u) * 2048u + (lo % 3136u)) % 3136u);
}

// ---------------- selection-grade f32 GEMM -> TRANSPOSED qT[bh][d][n] ----------------
__global__ __launch_bounds__(256) void qselT_k(const void* __restrict__ xr, const void* __restrict__ wr,
                                               const int* __restrict__ flagp, float* __restrict__ qt)
{
  __shared__ float As[128 * 20];
  __shared__ float Bs[16 * 64];
  const int t = threadIdx.x;
  const int m0 = blockIdx.x * 128;
  const int n0 = blockIdx.y * 64;
  const int f32i = flagp[0];
  const int tx = t & 15, ty = t >> 4;
  float acc[8][4];
  #pragma unroll
  for (int i = 0; i < 8; ++i)
    #pragma unroll
    for (int j = 0; j < 4; ++j) acc[i][j] = 0.f;

  const int alr = t >> 1;               // A tile row (0..127)
  const int alk = (t & 1) * 8;          // A k offset (0 or 8)
  const int bkr = t >> 4;               // B k row (0..15)
  const int bnc = (t & 15) * 4;         // B col offset

  for (int k0 = 0; k0 < 768; k0 += 16) {
    float av[8];
    float4 bv;
    if (f32i) {
      const float* xa = (const float*)xr + (size_t)(m0 + alr) * 768 + k0 + alk;
      float4 a0 = *(const float4*)(xa);
      float4 a1 = *(const float4*)(xa + 4);
      av[0] = a0.x; av[1] = a0.y; av[2] = a0.z; av[3] = a0.w;
      av[4] = a1.x; av[5] = a1.y; av[6] = a1.z; av[7] = a1.w;
      bv = *(const float4*)((const float*)wr + (size_t)(k0 + bkr) * 2304 + n0 + bnc);
    } else {
      const u16* xa = (const u16*)xr + (size_t)(m0 + alr) * 768 + k0 + alk;
      #pragma unroll
      for (int j = 0; j < 8; ++j) av[j] = b2f(xa[j]);
      const u16* wa = (const u16*)wr + (size_t)(k0 + bkr) * 2304 + n0 + bnc;
      bv.x = b2f(wa[0]); bv.y = b2f(wa[1]); bv.z = b2f(wa[2]); bv.w = b2f(wa[3]);
    }
    #pragma unroll
    for (int j = 0; j < 8; ++j) As[alr * 20 + alk + j] = av[j];
    *(float4*)(&Bs[bkr * 64 + bnc]) = bv;
    __syncthreads();
    #pragma unroll
    for (int kk = 0; kk < 16; ++kk) {
      float a[8], b[4];
      #pragma unroll
      for (int i = 0; i < 8; ++i) a[i] = As[(ty * 8 + i) * 20 + kk];
      #pragma unroll
      for (int j = 0; j < 4; ++j) b[j] = Bs[kk * 64 + tx * 4 + j];
      #pragma unroll
      for (int i = 0; i < 8; ++i)
        #pragma unroll
        for (int j = 0; j < 4; ++j) acc[i][j] += a[i] * b[j];
    }
    __syncthreads();
  }
  #pragma unroll
  for (int i = 0; i < 8; ++i) {
    const int m = m0 + ty * 8 + i;
    const int b = m / N_, n = m - b * N_;
    #pragma unroll
    for (int j = 0; j < 4; ++j) {
      const int col = n0 + tx * 4 + j;
      const int hh = col >> 6, dd = col & 63;
      qt[((size_t)(b * H_ + hh) * 64 + dd) * N_ + n] = acc[i][j] * SC_;
    }
  }
}

// ---------------- greedy landmarks: 8 blocks/head, data-carrying single-RTT barrier ----
// Slot (par,kb): word0 = packed candidate [63:19]=trunc f64 val |[18:12]=tag|[11:0]=idx;
// word1/2 = tag<<32 | lo/hi32 of f64 inv_own of candidate row; words 3..66 =
// tag<<32 | f32 bits of candidate column d=0..63. All relaxed agent atomics;
// every word self-tagged -> no ordering required; parity prevents race-around.
__global__ __launch_bounds__(512, 1) void landmarksB_k(
    const float* __restrict__ qt, float* __restrict__ lm, u64* __restrict__ cand)
{
  const int kb = blockIdx.y;   // grid (24, KB_): all 8 blocks of a head on one XCD
  const int bh = blockIdx.x;
  const float* QT = qt + (size_t)bh * 64 * N_;   // [d][n]
  float* LM = lm + (size_t)bh * L_ * 64;
  u64* cd = cand + (size_t)bh * (2 * KB_ * SLOTW_);
  __shared__ double curD[64];
  __shared__ u64 redV[8];
  __shared__ int redI[8];
  __shared__ u64 sMyVal;
  __shared__ int sMyIx;
  __shared__ int sW;
  const int t = threadIdx.x;
  const bool act = (t < RPB_);
  const int g = t >> 2, dc = t & 3, d0 = dc * 16;
  const int r0 = kb * RPB_;
  const int myRow = r0 + t;
  const float* base = QT + r0 + 4 * g;

  float4 qreg[16];
  #pragma unroll
  for (int i = 0; i < 16; ++i) qreg[i] = (float4){0.f, 0.f, 0.f, 0.f};
  if (act) {
    #pragma unroll
    for (int i = 0; i < 16; ++i) qreg[i] = *(const float4*)(base + (size_t)(d0 + i) * N_);
  }

  // norms (f64 from f32): quad-split + butterfly (R9-proven order)
  double inv_own = 0.0, ms_own = 0.0;
  if (act) {
    double s0 = 0.0, s1 = 0.0, s2 = 0.0, s3 = 0.0;
    #pragma unroll
    for (int i = 0; i < 16; ++i) {
      const float4 v = qreg[i];
      s0 += (double)v.x * (double)v.x; s1 += (double)v.y * (double)v.y;
      s2 += (double)v.z * (double)v.z; s3 += (double)v.w * (double)v.w;
    }
    s0 += __shfl_xor(s0, 1); s1 += __shfl_xor(s1, 1);
    s2 += __shfl_xor(s2, 1); s3 += __shfl_xor(s3, 1);
    s0 += __shfl_xor(s0, 2); s1 += __shfl_xor(s1, 2);
    s2 += __shfl_xor(s2, 2); s3 += __shfl_xor(s3, 2);
    const double sown = (dc == 0) ? s0 : (dc == 1) ? s1 : (dc == 2) ? s2 : s3;
    inv_own = 1.0 / fmax(sqrt(sown), 1e-12);
  }
  const int idx0 = tf_idx0(bh);
  if (act && myRow == idx0) ms_own = 10.0;

  // initial direction: one-time gather + butterfly (R8-proven init math)
  if (t < 64) {
    const float vf = QT[(size_t)t * N_ + idx0];
    double v = (double)vf;
    double s = v * v;
    #pragma unroll
    for (int off = 32; off; off >>= 1) s += __shfl_xor(s, off);
    curD[t] = v / fmax(sqrt(s), 1e-12);
    if (kb == 0) LM[t] = vf;
  }
  __syncthreads();

  for (int step = 1; step < 128; ++step) {
    u64 bV = d2u(1e30); int bI = 0x7fffffff;
    if (act) {
      double a0 = 0.0, a1 = 0.0, a2 = 0.0, a3 = 0.0;
      #pragma unroll
      for (int i = 0; i < 16; ++i) {
        const float4 v = qreg[i];
        const double c = curD[d0 + i];
        a0 += (double)v.x * c; a1 += (double)v.y * c;
        a2 += (double)v.z * c; a3 += (double)v.w * c;
      }
      a0 += __shfl_xor(a0, 1); a1 += __shfl_xor(a1, 1);
      a2 += __shfl_xor(a2, 1); a3 += __shfl_xor(a3, 1);
      a0 += __shfl_xor(a0, 2); a1 += __shfl_xor(a1, 2);
      a2 += __shfl_xor(a2, 2); a3 += __shfl_xor(a3, 2);
      const double aown = (dc == 0) ? a0 : (dc == 1) ? a1 : (dc == 2) ? a2 : a3;
      ms_own = fmax(ms_own, fabs(aown * inv_own));
      bV = d2u(ms_own); bI = myRow;   // nonneg doubles: bit order == numeric order
    }
    // wave argmin (val, then lowest idx)
    #pragma unroll
    for (int off = 32; off; off >>= 1) {
      const u64 ov = __shfl_xor(bV, off);
      const int oi = __shfl_xor(bI, off);
      if (ov < bV || (ov == bV && oi < bI)) { bV = ov; bI = oi; }
    }
    if ((t & 63) == 0) { redV[t >> 6] = bV; redI[t >> 6] = bI; }
    __syncthreads();
    const int par = step & 1;
    u64* slot = cd + (size_t)(par * KB_ + kb) * SLOTW_;
    if (t == 0) {
      u64 v = redV[0]; int ix = redI[0];
      #pragma unroll
      for (int w2 = 1; w2 < 8; ++w2)
        if (redV[w2] < v || (redV[w2] == v && redI[w2] < ix)) { v = redV[w2]; ix = redI[w2]; }
      sMyVal = v; sMyIx = ix;
    }
    __syncthreads();
    const int mix = sMyIx;
    const u64 tg = (u64)(u32)step << 32;
    // publish: owning quad writes the candidate column (tagged words)
    if (act && (t >> 2) == ((mix - r0) >> 2)) {
      const int j = (mix - r0) & 3;
      #pragma unroll
      for (int i = 0; i < 16; ++i) {
        const float4 v4 = qreg[i];
        float vv = v4.x;
        if (j == 1) vv = v4.y; else if (j == 2) vv = v4.z; else if (j == 3) vv = v4.w;
        u32 fb; __builtin_memcpy(&fb, &vv, 4);
        __hip_atomic_store(&slot[3 + d0 + i], tg | (u64)fb, __ATOMIC_RELAXED, __HIP_MEMORY_SCOPE_AGENT);
      }
    }
    if (act && myRow == mix) {   // candidate row owner publishes its inv-norm
      const u64 ib = d2u(inv_own);
      __hip_atomic_store(&slot[1], tg | (u64)(u32)ib, __ATOMIC_RELAXED, __HIP_MEMORY_SCOPE_AGENT);
      __hip_atomic_store(&slot[2], tg | (u64)(u32)(ib >> 32), __ATOMIC_RELAXED, __HIP_MEMORY_SCOPE_AGENT);
    }
    if (t == 0) {
      const u64 pk = (sMyVal & ~((1ull << 19) - 1ull)) | ((u64)(u32)(step & 127) << 12) | (u64)(u32)mix;
      __hip_atomic_store(&slot[0], pk, __ATOMIC_RELAXED, __HIP_MEMORY_SCOPE_AGENT);
    }
    // single-RTT poll: columns read speculatively alongside candidates
    if (t < 64) {
      u64 colw[KB_];
      u64 aux = 0;
      for (;;) {
        bool ok = true;
        #pragma unroll
        for (int s = 0; s < KB_; ++s) {
          colw[s] = __hip_atomic_load(&cd[(size_t)(par * KB_ + s) * SLOTW_ + 3 + t],
                                      __ATOMIC_RELAXED, __HIP_MEMORY_SCOPE_AGENT);
          ok = ok && ((int)(colw[s] >> 32) == step);
        }
        if (t < KB_) {
          aux = __hip_atomic_load(&cd[(size_t)(par * KB_ + t) * SLOTW_],
                                  __ATOMIC_RELAXED, __HIP_MEMORY_SCOPE_AGENT);
          ok = ok && ((int)((aux >> 12) & 127u) == (step & 127));
        } else if (t < 2 * KB_) {
          aux = __hip_atomic_load(&cd[(size_t)(par * KB_ + (t - KB_)) * SLOTW_ + 1],
                                  __ATOMIC_RELAXED, __HIP_MEMORY_SCOPE_AGENT);
          ok = ok && ((int)(aux >> 32) == step);
        } else if (t < 3 * KB_) {
          aux = __hip_atomic_load(&cd[(size_t)(par * KB_ + (t - 2 * KB_)) * SLOTW_ + 2],
                                  __ATOMIC_RELAXED, __HIP_MEMORY_SCOPE_AGENT);
          ok = ok && ((int)(aux >> 32) == step);
        }
        if (__all(ok)) break;
      }
      // winner among lanes 0..7 (u64 min == lexical (val,idx) min)
      u64 m = (t < KB_) ? aux : ~0ull;
      int msl = t & 7;
      #pragma unroll
      for (int off = 1; off < KB_; off <<= 1) {
        const u64 o = __shfl_xor(m, off);
        const int os = __shfl_xor(msl, off);
        if (o < m) { m = o; msl = os; }
      }
      const int wkb = __shfl(msl, 0);
      const u64 wv = __shfl(m, 0);
      const u32 ilo = (u32)__shfl(aux, KB_ + wkb);
      const u32 ihi = (u32)__shfl(aux, 2 * KB_ + wkb);
      const double invW = u2d(((u64)ihi << 32) | (u64)ilo);
      u64 cw = colw[0];
      #pragma unroll
      for (int s = 1; s < KB_; ++s) cw = (wkb == s) ? colw[s] : cw;   // cndmask chain
      const u32 fb = (u32)cw;
      float vf; __builtin_memcpy(&vf, &fb, 4);
      curD[t] = (double)vf * invW;            // R9-proven mul-by-reciprocal form
      if (kb == 0) LM[(size_t)step * 64 + t] = vf;
      if (t == 0) sW = (int)(wv & 0xFFFu);
    }
    __syncthreads();
    const int w = sW;
    if (act && myRow == w) ms_own = 10.0;
  }
}

// ---------------- weight transpose + bf16-ify: W[K][Nn] raw -> WT[Nn][K] bf16 ----------------
__device__ __forceinline__ void twT_body(const void* W, int K, int Nn, int f32i,
                                         u16* WT, int k0, int n0, int t, u16 (&Ts)[64][80])
{
  const int kr = t >> 2, nc = (t & 3) * 16;
  u16 tmp[16];
  if (f32i) {
    const float* p = (const float*)W + (size_t)(k0 + kr) * Nn + n0 + nc;
    #pragma unroll
    for (int j = 0; j < 16; ++j) tmp[j] = f2b(p[j]);
  } else {
    const u16* p = (const u16*)W + (size_t)(k0 + kr) * Nn + n0 + nc;
    #pragma unroll
    for (int j = 0; j < 16; ++j) tmp[j] = p[j];
  }
  #pragma unroll
  for (int j = 0; j < 16; ++j) Ts[kr][nc + j] = tmp[j];
  __syncthreads();
  const int nr = t >> 2, kc = (t & 3) * 16;
  u16 o[16];
  #pragma unroll
  for (int j = 0; j < 16; ++j) o[j] = Ts[kc + j][nr];
  u16* dst = WT + (size_t)(n0 + nr) * K + k0 + kc;
  *(uint4*)(dst) = *(uint4*)(o);
  *(uint4*)(dst + 8) = *(uint4*)(o + 8);
}

__global__ __launch_bounds__(256) void twT_k(const void* __restrict__ W, int K, int Nn,
                                             const int* __restrict__ flagp, u16* __restrict__ WT)
{
  __shared__ u16 Ts[64][80];
  twT_body(W, K, Nn, flagp[0], WT, blockIdx.x * 64, blockIdx.y * 64, threadIdx.x, Ts);
}

// merged: z=0 Wpkv^T, z=1 Wpq^T, z=2 Wproj^T, z=3 Wpkv plain bf16 copy (original layout)
__global__ __launch_bounds__(256) void twT3_k(const void* __restrict__ W0, const void* __restrict__ W1,
                                              const void* __restrict__ W2, const int* __restrict__ flagp,
                                              u16* __restrict__ T0, u16* __restrict__ T1, u16* __restrict__ T2,
                                              u16* __restrict__ Wb)
{
  __shared__ u16 Ts[64][80];
  const int z = blockIdx.z;
  const int t = threadIdx.x;
  if (z == 3) {                       // plain convert Wpkv [768][1536] -> bf16
    const int k0 = blockIdx.x * 64, n0 = blockIdx.y * 64;
    const int kr = t >> 2, nc = (t & 3) * 16;
    u16 tmp[16];
    if (flagp[0]) {
      const float* p = (const float*)W0 + (size_t)(k0 + kr) * 1536 + n0 + nc;
      #pragma unroll
      for (int j = 0; j < 16; ++j) tmp[j] = f2b(p[j]);
    } else {
      const u16* p = (const u16*)W0 + (size_t)(k0 + kr) * 1536 + n0 + nc;
      #pragma unroll
      for (int j = 0; j < 16; ++j) tmp[j] = p[j];
    }
    u16* dst = Wb + (size_t)(k0 + kr) * 1536 + n0 + nc;
    *(uint4*)(dst) = *(uint4*)(tmp);
    *(uint4*)(dst + 8) = *(uint4*)(tmp + 8);
    return;
  }
  const void* W = (z == 0) ? W0 : (z == 1) ? W1 : W2;
  u16* WT = (z == 0) ? T0 : (z == 1) ? T1 : T2;
  const int Nn = (z == 0) ? 1536 : 768;
  if (blockIdx.y * 64 >= Nn) return;
  twT_body(W, 768, Nn, flagp[0], WT, blockIdx.x * 64, blockIdx.y * 64, t, Ts);
}

// ---------------- x -> bf16 (elementwise, 8/thread, 4816896 elems) ----------------
__global__ __launch_bounds__(256) void xcvt_k(const void* __restrict__ x,
                                              const int* __restrict__ flagp, u16* __restrict__ xb)
{
  const int i = blockIdx.x * 256 + threadIdx.x;  // 602112 threads exactly
  if (flagp[0]) {
    const float4* p = (const float4*)x + (size_t)i * 2;
    float4 f0 = p[0], f1 = p[1];
    u16 tmp[8] = { f2b(f0.x), f2b(f0.y), f2b(f0.z), f2b(f0.w),
                   f2b(f1.x), f2b(f1.y), f2b(f1.z), f2b(f1.w) };
    *(uint4*)(xb + (size_t)i * 8) = *(uint4*)tmp;
  } else {
    ((uint4*)xb)[i] = ((const uint4*)x)[i];
  }
}

// ---------------- shared GEMM core: global_load_lds staging + swizzled ds_read ----
struct GemmCore {
  const u16 *aP0, *aP1, *bP0, *bP1;
  u16 *lA0, *lA1, *lB0, *lB1;
  int roA[4], roB[4];
  int mw, nw, lr, lk;
};

__device__ __forceinline__ void gemm_core_init(GemmCore& gc, u16* As, u16* Bs,
    const u16* A16, const u16* B16, size_t aOff, size_t bOff,
    int m0, int n0, int lda, int ldb, int M, int t)
{
  const int lane = t & 63;
  const int w = t >> 6;
  gc.mw = (w >> 1) * 64;
  gc.nw = (w & 1) * 64;
  gc.lr = lane & 15;
  gc.lk = lane >> 4;
  const int c0 = w * 2, c1 = c0 + 1;
  const int rl = lane >> 2, sl = lane & 3;
  const int rowA0 = c0 * 16 + rl, rowA1 = c1 * 16 + rl;
  const int segA0 = (sl ^ ((rowA0 ^ (rowA0 >> 2)) & 3)) * 8;
  const int segA1 = (sl ^ ((rowA1 ^ (rowA1 >> 2)) & 3)) * 8;
  int ga0 = m0 + rowA0; if (ga0 >= M) ga0 = M - 1;
  int ga1 = m0 + rowA1; if (ga1 >= M) ga1 = M - 1;
  gc.aP0 = A16 + aOff + (size_t)ga0 * lda + segA0;
  gc.aP1 = A16 + aOff + (size_t)ga1 * lda + segA1;
  gc.bP0 = B16 + bOff + (size_t)(n0 + rowA0) * ldb + segA0;
  gc.bP1 = B16 + bOff + (size_t)(n0 + rowA1) * ldb + segA1;
  gc.lA0 = &As[c0 * 512]; gc.lA1 = &As[c1 * 512];
  gc.lB0 = &Bs[c0 * 512]; gc.lB1 = &Bs[c1 * 512];
  #pragma unroll
  for (int q = 0; q < 4; ++q) {
    const int ra = gc.mw + q * 16 + gc.lr;
    gc.roA[q] = ra * 32 + ((gc.lk ^ ((ra ^ (ra >> 2)) & 3)) * 8);
    const int rb = gc.nw + q * 16 + gc.lr;
    gc.roB[q] = rb * 32 + ((gc.lk ^ ((rb ^ (rb >> 2)) & 3)) * 8);
  }
}

__device__ __forceinline__ void gemm_core_loop(const GemmCore& gc, u16* As, u16* Bs,
                                               int K, f32x4 (&acc)[4][4])
{
  for (int k0 = 0; k0 < K; k0 += 32) {
    gll16(gc.aP0 + k0, gc.lA0);
    gll16(gc.aP1 + k0, gc.lA1);
    gll16(gc.bP0 + k0, gc.lB0);
    gll16(gc.bP1 + k0, gc.lB1);
    __syncthreads();
    bf16x8 af[4], bfv[4];
    #pragma unroll
    for (int mt = 0; mt < 4; ++mt) af[mt] = *(const bf16x8*)(&As[gc.roA[mt]]);
    #pragma unroll
    for (int nt = 0; nt < 4; ++nt) bfv[nt] = *(const bf16x8*)(&Bs[gc.roB[nt]]);
    #pragma unroll
    for (int mt = 0; mt < 4; ++mt)
      #pragma unroll
      for (int nt = 0; nt < 4; ++nt)
        acc[mt][nt] = __builtin_amdgcn_mfma_f32_16x16x32_bf16(af[mt], bfv[nt], acc[mt][nt], 0, 0, 0);
    __syncthreads();
  }
}

// ---------------- generic 128x128 bf16 MFMA GEMM, per-mode epilogues ----
// MODE 0: qkv->qb,kb,vb | 1: xoc+xdc | 3: q2b | 4: final out | 5: g | 6: ob part
template <int MODE>
__global__ __launch_bounds__(256) void gemm_k(
    const void* __restrict__ Ap, const void* __restrict__ Bp,
    int M, int K, int lda, int ldb, int n0c, int cn, const int* __restrict__ flagp,
    float* __restrict__ of0, u16* __restrict__ ob0, u16* __restrict__ ob1, u16* __restrict__ ob2,
    const void* __restrict__ biasRaw, void* __restrict__ outRaw)
{
  __shared__ u16 As[128 * 32];
  __shared__ u16 Bs[128 * 32];
  const int t = threadIdx.x;
  const int m0 = blockIdx.x * 128;
  const int n0 = blockIdx.y * 128;
  const int rf = (MODE == 4) ? flagp[0] : 0;

  size_t aOff = 0, bOff = 0;
  if constexpr (MODE == 1) {
    const int bh = blockIdx.z;
    aOff = (size_t)bh * ((size_t)N_ * 128) + (size_t)n0c * 128;
    bOff = (size_t)bh * (1024 * 128);
  }
  if constexpr (MODE == 5) {
    const int h = blockIdx.z;
    aOff = (size_t)h * (2 * cn) * 64;
    bOff = (size_t)h * 64;
  }
  if constexpr (MODE == 6) {
    const int h = blockIdx.z;
    aOff = (size_t)h * (2 * cn) * 768;
    bOff = (size_t)(768 + h * 64) * 768;
  }
  f32x4 acc[4][4];
  #pragma unroll
  for (int i = 0; i < 4; ++i)
    #pragma unroll
    for (int j = 0; j < 4; ++j) acc[i][j] = (f32x4){0.f, 0.f, 0.f, 0.f};

  GemmCore gc;
  gemm_core_init(gc, As, Bs, (const u16*)Ap, (const u16*)Bp, aOff, bOff, m0, n0, lda, ldb, M, t);
  gemm_core_loop(gc, As, Bs, K, acc);

  const int lr = gc.lr, lk = gc.lk, mw = gc.mw, nw = gc.nw;
  #pragma unroll
  for (int mt = 0; mt < 4; ++mt) {
    #pragma unroll
    for (int nt = 0; nt < 4; ++nt) {
      #pragma unroll
      for (int r = 0; r < 4; ++r) {
        const int grow = m0 + mw + mt * 16 + lk * 4 + r;
        const int gcol = n0 + nw + nt * 16 + lr;
        if (grow >= M) continue;
        float vv = acc[mt][nt][r];
        if constexpr (MODE == 0) {           // qkv -> qb,kb,vb bf16 (bh,N,64)
          int b = (grow >= N_) ? 1 : 0;
          int n = grow - b * N_;
          int t3 = gcol / C_, cc = gcol - t3 * C_;
          int hh = cc >> 6, dd = cc & 63;
          size_t dst = (((size_t)(b * H_ + hh)) * N_ + n) * 64 + dd;
          if (t3 == 0) ob0[dst] = f2b(vv * SC_);
          else if (t3 == 1) ob1[dst] = f2b(vv * SC_);
          else ob2[dst] = f2b(vv);
        } else if constexpr (MODE == 1) {    // xoc (B,cn,F,C) bf16 + xdiag side-write
          const int bh = blockIdx.z;
          int b = bh / H_, hh = bh - b * H_;
          int f = gcol >> 6, dd = gcol & 63;
          u16 wv = f2b(vv);
          ob0[(((size_t)(b * cn + grow)) * F_ + f) * C_ + hh * 64 + dd] = wv;
          int n = n0c + grow;
          if (f == n / P_) ob1[((size_t)(b * cn + grow)) * C_ + hh * 64 + dd] = wv;
        } else if constexpr (MODE == 3) {    // q2b [h][2cn][64] bf16, * 0.125
          int hh = gcol >> 6, dd = gcol & 63;
          ob0[((size_t)hh * (2 * cn) + grow) * 64 + dd] = f2b(vv * 0.125f);
        } else if constexpr (MODE == 5) {    // g [h][2cn][768] bf16
          ob0[((size_t)blockIdx.z * (2 * cn) + grow) * 768 + gcol] = f2b(vv);
        } else if constexpr (MODE == 6) {    // ob part: out_h = wc_h @ Wpkv_v_h
          if (gcol < 64) {
            int b2 = (grow >= cn) ? 1 : 0;
            int ln = grow - b2 * cn;
            ob0[((size_t)(b2 * N_ + n0c + ln)) * 768 + blockIdx.z * 64 + gcol] = f2b(vv);
          }
        } else {                             // MODE 4: out = o@W_proj + b_proj
          float bvad = rf ? ((const float*)biasRaw)[gcol] : b2f(((const u16*)biasRaw)[gcol]);
          float ov = vv + bvad;
          if (rf) ((float*)outRaw)[(size_t)grow * C_ + gcol] = ov;
          else    ((u16*)outRaw)[(size_t)grow * C_ + gcol] = f2b(ov);
        }
      }
    }
  }
}

// ---------------- kernel_1 = softmax_l(q . lm^T), bf16 out ----------------
__global__ __launch_bounds__(256) void k1_k(const u16* __restrict__ qb,
                                            const float* __restrict__ lm,
                                            u16* __restrict__ k1)
{
  const int bh = blockIdx.y;
  const int r0 = blockIdx.x * 64;
  __shared__ float qT[64][65];
  __shared__ float lmS[128 * 64];
  __shared__ float redA[4][64];
  __shared__ float redB[64];
  const int t = threadIdx.x;
  const u16* Q = qb + ((size_t)bh * N_ + r0) * 64;
  const float* Lm = lm + (size_t)bh * L_ * 64;
  for (int u = t; u < 2048; u += 256) ((float4*)lmS)[u] = ((const float4*)Lm)[u];
  for (int u = t; u < 512; u += 256) {
    int row = u >> 3, j0 = (u & 7) * 8;
    uint4 pk = *(const uint4*)(Q + (size_t)row * 64 + j0);
    const u16* pu = (const u16*)&pk;
    #pragma unroll
    for (int jj = 0; jj < 8; ++jj) qT[j0 + jj][row] = b2f(pu[jj]);
  }
  __syncthreads();
  const int row = t & 63, ch = t >> 6;
  float qr[64];
  #pragma unroll
  for (int j = 0; j < 64; ++j) qr[j] = qT[j][row];
  float s[32];
  for (int li = 0; li < 32; ++li) {
    const float* lp = lmS + (ch * 32 + li) * 64;
    float a = 0.f;
    #pragma unroll
    for (int j = 0; j < 64; ++j) a += lp[j] * qr[j];
    s[li] = a;
  }
  float mx = -1e30f;
  for (int li = 0; li < 32; ++li) mx = fmaxf(mx, s[li]);
  redA[ch][row] = mx;
  __syncthreads();
  if (t < 64) redB[t] = fmaxf(fmaxf(redA[0][t], redA[1][t]), fmaxf(redA[2][t], redA[3][t]));
  __syncthreads();
  mx = redB[row];
  float sum = 0.f;
  for (int li = 0; li < 32; ++li) { float e = __expf(s[li] - mx); s[li] = e; sum += e; }
  __syncthreads();
  redA[ch][row] = sum;
  __syncthreads();
  if (t < 64) redB[t] = 1.0f / (redA[0][t] + redA[1][t] + redA[2][t] + redA[3][t]);
  __syncthreads();
  const float inv = redB[row];
  u16* out = k1 + ((size_t)bh * N_ + r0 + row) * 128 + ch * 32;
  for (int li = 0; li < 32; ++li) out[li] = f2b(s[li] * inv);
}

// ---------------- kernel_2 per frame + x1 = kernel_2 @ v  (LDS-only, 3-pass) ----------------
// x1 written TRANSPOSED: x1T[bh][n = f*64+dd][l], coalesced per-u across lanes.
__global__ __launch_bounds__(256) void k2x1_k(const float* __restrict__ lm,
                                              const u16* __restrict__ kb,
                                              const u16* __restrict__ vb,
                                              u16* __restrict__ x1)
{
  const int bh = blockIdx.x;
  const int f = blockIdx.y;
  __shared__ u16 kS[P_ * 64];
  __shared__ u16 vS[P_ * 64];
  __shared__ float redM[2][128];
  __shared__ float redS[2][128];
  const int t = threadIdx.x;
  const u16* Kf = kb + ((size_t)bh * N_ + f * P_) * 64;
  const u16* Vf = vb + ((size_t)bh * N_ + f * P_) * 64;
  for (int u = t; u < 1568; u += 256) {
    ((uint4*)kS)[u] = ((const uint4*)Kf)[u];
    ((uint4*)vS)[u] = ((const uint4*)Vf)[u];
  }
  __syncthreads();
  const int l = t & 127, half = t >> 7;
  const float* lp = lm + ((size_t)bh * L_ + l) * 64;
  float lr[64];
  #pragma unroll
  for (int j = 0; j < 64; ++j) lr[j] = lp[j];

  const int p0 = half * 98, p1 = p0 + 98;
  float mx = -1e30f;
  for (int p = p0; p < p1; ++p) {
    const uint4* kp = (const uint4*)(kS + p * 64);
    float s = 0.f;
    #pragma unroll
    for (int q4 = 0; q4 < 8; ++q4) {
      uint4 pk = kp[q4];
      const u32* pu = (const u32*)&pk;
      #pragma unroll
      for (int j2 = 0; j2 < 4; ++j2) {
        u32 u = pu[j2];
        s += lr[q4 * 8 + j2 * 2] * lo16f(u) + lr[q4 * 8 + j2 * 2 + 1] * hi16f(u);
      }
    }
    mx = fmaxf(mx, s);
  }
  redM[half][l] = mx;
  __syncthreads();
  mx = fmaxf(redM[0][l], redM[1][l]);

  float sm = 0.f;
  for (int p = p0; p < p1; ++p) {
    const uint4* kp = (const uint4*)(kS + p * 64);
    float s = 0.f;
    #pragma unroll
    for (int q4 = 0; q4 < 8; ++q4) {
      uint4 pk = kp[q4];
      const u32* pu = (const u32*)&pk;
      #pragma unroll
      for (int j2 = 0; j2 < 4; ++j2) {
        u32 u = pu[j2];
        s += lr[q4 * 8 + j2 * 2] * lo16f(u) + lr[q4 * 8 + j2 * 2 + 1] * hi16f(u);
      }
    }
    sm += __expf(s - mx);
  }
  redS[half][l] = sm;
  __syncthreads();
  const float inv = 1.0f / (redS[0][l] + redS[1][l]);

  const int dd0 = half * 32;
  float acc[32];
  #pragma unroll
  for (int u = 0; u < 32; ++u) acc[u] = 0.f;
  for (int p = 0; p < P_; ++p) {
    const uint4* kp = (const uint4*)(kS + p * 64);
    float s = 0.f;
    #pragma unroll
    for (int q4 = 0; q4 < 8; ++q4) {
      uint4 pk = kp[q4];
      const u32* pu = (const u32*)&pk;
      #pragma unroll
      for (int j2 = 0; j2 < 4; ++j2) {
        u32 u = pu[j2];
        s += lr[q4 * 8 + j2 * 2] * lo16f(u) + lr[q4 * 8 + j2 * 2 + 1] * hi16f(u);
      }
    }
    const float e = __expf(s - mx);
    const uint4* vp = (const uint4*)(vS + p * 64 + dd0);
    #pragma unroll
    for (int q4 = 0; q4 < 4; ++q4) {
      uint4 pv = vp[q4];
      const u32* pu = (const u32*)&pv;
      #pragma unroll
      for (int j2 = 0; j2 < 4; ++j2) {
        u32 u = pu[j2];
        acc[q4 * 8 + j2 * 2]     += e * lo16f(u);
        acc[q4 * 8 + j2 * 2 + 1] += e * hi16f(u);
      }
    }
  }
  // transposed store: x1T[bh][f*64 + dd][l]; per-u the 128 l-lanes are contiguous
  u16* outT = x1 + (size_t)bh * (1024 * 128) + (size_t)(f * 64 + dd0) * 128 + l;
  for (int u = 0; u < 32; ++u) outT[(size_t)u * 128] = f2b(acc[u] * inv);
}

// ---------------- reassociated attention: logits = g.Xo, softmax, w = attn.Xo ----------------
// one block per token m=(b,ln). wc written IN PLACE of g (same indices; g row
// dead after phase 1; blocks touch only their own m row -> no cross hazard).
__global__ __launch_bounds__(256) void attn2_k(const u16* __restrict__ xoc,
                                               const u16* __restrict__ g,
                                               int n0c, int cn, const int* __restrict__ flagp,
                                               void* __restrict__ outRaw, u16* __restrict__ wc)
{
  __shared__ float aS[12][16];
  const int t = threadIdx.x;
  const int m = blockIdx.x;
  const int b = (m >= cn) ? 1 : 0;
  const int ln = m - b * cn;
  const int n = n0c + ln;
  const int f32o = flagp[0];
  const u16* Xo = xoc + ((size_t)(b * cn + ln) * 16) * 768;
  const size_t hstr = (size_t)(2 * cn) * 768;

  if (t < 192) {
    const int h = t >> 4, f = t & 15;
    const uint4* xp = (const uint4*)(Xo + (size_t)f * 768);
    const uint4* gp = (const uint4*)(g + (size_t)h * hstr + (size_t)m * 768);
    float lg = 0.f;
    #pragma unroll 4
    for (int q = 0; q < 96; ++q) {
      uint4 xv = xp[q], gv = gp[q];
      const u32* xu = (const u32*)&xv;
      const u32* gu = (const u32*)&gv;
      #pragma unroll
      for (int j = 0; j < 4; ++j)
        lg += lo16f(xu[j]) * lo16f(gu[j]) + hi16f(xu[j]) * hi16f(gu[j]);
    }
    float mx = lg;
    mx = fmaxf(mx, __shfl_xor(mx, 1));
    mx = fmaxf(mx, __shfl_xor(mx, 2));
    mx = fmaxf(mx, __shfl_xor(mx, 4));
    mx = fmaxf(mx, __shfl_xor(mx, 8));
    float e = __expf(lg - mx);
    float sm = e;
    sm += __shfl_xor(sm, 1);
    sm += __shfl_xor(sm, 2);
    sm += __shfl_xor(sm, 4);
    sm += __shfl_xor(sm, 8);
    const float a = e / sm;
    const size_t abase = ((size_t)(b * H_ + h) * N_ + n) * F_ + f;
    if (f32o) ((float*)outRaw)[OUTPART_ + abase] = a;
    else      ((u16*)outRaw)[OUTPART_ + abase] = f2b(a);
    aS[h][f] = a;
  }
  __syncthreads();
  if (t < 192) {
    const int cg = t >> 1, sh = t & 1;
    const int c0 = cg * 8;
    float acc[6][8];
    #pragma unroll
    for (int j = 0; j < 6; ++j)
      #pragma unroll
      for (int k = 0; k < 8; ++k) acc[j][k] = 0.f;
    for (int f = 0; f < 16; ++f) {
      uint4 xv = *(const uint4*)(Xo + (size_t)f * 768 + c0);
      const u32* xu = (const u32*)&xv;
      float xf[8];
      #pragma unroll
      for (int j = 0; j < 4; ++j) { xf[2 * j] = lo16f(xu[j]); xf[2 * j + 1] = hi16f(xu[j]); }
      #pragma unroll
      for (int j = 0; j < 6; ++j) {
        const float a = aS[sh * 6 + j][f];
        #pragma unroll
        for (int k = 0; k < 8; ++k) acc[j][k] += a * xf[k];
      }
    }
    #pragma unroll
    for (int j = 0; j < 6; ++j) {
      u16 pk[8];
      #pragma unroll
      for (int k = 0; k < 8; ++k) pk[k] = f2b(acc[j][k]);
      *(uint4*)(wc + (size_t)(sh * 6 + j) * hstr + (size_t)m * 768 + c0) = *(uint4*)pk;
    }
  }
}

extern "C" void kernel_launch(void* const* d_in, const int* in_sizes, int n_in,
                              void* d_out, int out_size, void* d_ws, size_t ws_size,
                              hipStream_t stream)
{
  (void)in_sizes; (void)n_in; (void)out_size;
  const void* x     = d_in[0];
  const void* Wqkv  = d_in[1];
  const void* Wpq   = d_in[2];
  const void* Wpkv  = d_in[3];
  const void* Wproj = d_in[4];
  const void* bproj = d_in[5];

  char* ws = (char*)d_ws;
  size_t off = 0;
  auto alloc = [&](size_t bytes) { void* p = ws + off; off += (bytes + 255) & ~(size_t)255; return p; };
  // ---- fixed region (live across the chunk loop) ----
  int*  flagp  = (int*)alloc(256);
  u16*  WpkvT  = (u16*)alloc(2359296);   // [1536][768] bf16
  u16*  WpqT   = (u16*)alloc(1179648);   // [768][768]
  u16*  WprojT = (u16*)alloc(1179648);   // [768][768]
  u16*  Wpkvb  = (u16*)alloc(2359296);   // [768][1536] bf16, original layout
  float* lm    = (float*)alloc(786432);  // (bh,128,64) f32
  u16*  x1b    = (u16*)alloc(6291456);   // (bh,1024,128) bf16 TRANSPOSED
  u16*  ob     = (u16*)alloc(9633792);   // (B,N,C) bf16
  u16*  k1b    = (u16*)alloc(19267584);  // (bh,N,128) bf16
  const size_t sc0 = off;                // scratch start (~43.1 MB)

  // ---- scratch overlays (time-multiplexed) ----
  // phase A (landmarks): qt 19.27MB + cand 245KB
  float* qt   = (float*)(ws + sc0);
  u64*   cand = (u64*)(ws + sc0 + 19267584);
  // phase B (projection): WqkvT 3.54 + xb 9.63 + qb/kbuf/vb 3x9.63 = 42.1MB
  u16* WqkvT = (u16*)(ws + sc0);
  u16* xb    = (u16*)(ws + sc0 + 3538944);
  u16* qb    = (u16*)(ws + sc0 + 13172736);
  u16* kbuf  = qb + 4816896;
  u16* vb    = kbuf + 4816896;
  // phase C (chunks): xoc + xdc + q2b + g(=wc in-place) = 46080 u16/Nc
  const size_t phaseB_need = sc0 + 42074112 + 1024;
  if (phaseB_need > ws_size) return;

  int Nc = 0;
  {
    const int cands[5] = {3136, 1568, 784, 392, 196};
    for (int i = 0; i < 5; ++i) {
      if (sc0 + (size_t)92160 * cands[i] + 1024 <= ws_size) { Nc = cands[i]; break; }
    }
  }
  if (Nc == 0) return;
  const int nchunks = N_ / Nc;
  u16* xoc = (u16*)(ws + sc0);            // (B,Nc,F,C) bf16
  u16* xdc = xoc + (size_t)24576 * Nc;    // (B,Nc,C) bf16
  u16* q2b = xdc + (size_t)1536 * Nc;     // [h][2Nc][64] bf16
  u16* gbf = q2b + (size_t)1536 * Nc;     // [h][2Nc][768] bf16; wc overwrites in place

  detect_k<<<1, 64, 0, stream>>>((const u32*)Wqkv, flagp);
  zcnt_k<<<60, 512, 0, stream>>>(cand);
  // weights to fixed region (independent of scratch) — run early
  twT3_k<<<dim3(12, 24, 4), 256, 0, stream>>>(Wpkv, Wpq, Wproj, flagp,
                                              WpkvT, WpqT, WprojT, Wpkvb);

  // selection-grade f32 qT (transposed), then single-RTT multi-block landmarks
  qselT_k<<<dim3(49, 12), 256, 0, stream>>>(x, Wqkv, flagp, qt);
  landmarksB_k<<<dim3(24, KB_), 512, 0, stream>>>(qt, lm, cand);

  // qt dead: build bf16 operands in its place
  twT_k<<<dim3(12, 36), 256, 0, stream>>>(Wqkv, 768, 2304, flagp, WqkvT);
  xcvt_k<<<2352, 256, 0, stream>>>(x, flagp, xb);

  // qkv projection -> qb,kbuf,vb (global_load_lds staging)
  gemm_k<0><<<dim3(49, 18, 1), 256, 0, stream>>>(xb, WqkvT, 6272, 768, 768, 768, 0, 0, flagp,
                                                 nullptr, qb, kbuf, vb, nullptr, nullptr);
  // kernel_2 + x1 (LDS-only, transposed x1 out)
  k2x1_k<<<dim3(24, 16), 256, 0, stream>>>(lm, kbuf, vb, x1b);
  // kernel_1
  k1_k<<<dim3(49, 24), 256, 0, stream>>>(qb, lm, k1b);

  const int gx = (2 * Nc + 127) / 128;
  for (int c = 0; c < nchunks; ++c) {
    const int n0c = c * Nc;
    // xo = k1 @ x1 (+ xdiag side-write)
    gemm_k<1><<<dim3((Nc + 127) / 128, 8, 24), 256, 0, stream>>>(
        k1b, x1b, Nc, 128, 128, 128, n0c, Nc, flagp, nullptr, xoc, xdc, nullptr, nullptr, nullptr);
    // q2b = bf16(xdiag @ Wpq * 0.125), [h][2Nc][64]
    gemm_k<3><<<dim3(gx, 6, 1), 256, 0, stream>>>(
        xdc, WpqT, 2 * Nc, 768, 768, 768, n0c, Nc, flagp, nullptr, q2b, nullptr, nullptr, nullptr, nullptr);
    // g = bf16(q2b @ Wpkv_k^T), K=64, per-head
    gemm_k<5><<<dim3(gx, 6, 12), 256, 0, stream>>>(
        q2b, Wpkvb, 2 * Nc, 64, 64, 1536, n0c, Nc, flagp, nullptr, gbf, nullptr, nullptr, nullptr, nullptr);
    // logits = g.Xo -> softmax -> attn out + w = attn.Xo (wc in place of g)
    attn2_k<<<dim3(2 * Nc), 256, 0, stream>>>(xoc, gbf, n0c, Nc, flagp, d_out, gbf);
    // ob_h = wc_h @ Wpkv_v_h (N=64 masked)
    gemm_k<6><<<dim3(gx, 1, 12), 256, 0, stream>>>(
        gbf, WpkvT, 2 * Nc, 768, 768, 768, n0c, Nc, flagp, nullptr, ob, nullptr, nullptr, nullptr, nullptr);
  }
  // out = o @ W_proj + b_proj
  gemm_k<4><<<dim3(49, 6, 1), 256, 0, stream>>>(ob, WprojT, 6272, 768, 768, 768, 0, 0, flagp,
                                                nullptr, nullptr, nullptr, nullptr, bproj, d_out);
}

// Round 9
// 1521.653 us; speedup vs baseline: 1.2725x; 1.2725x over previous
//
#include <hip/hip_runtime.h>

// TrajectoryAttention on MI355X (gfx950), chunked pipeline, dtype-adaptive.
// R17: REVERT landmarks to R15's proven landmarksR_k (packed-u64 fence-free
//   barrier, 392us). R16's data-carrying barrier regressed 2x: 67 tagged
//   atomic stores/step/block + poll-until-all-visible made the step gate on
//   the slowest of 536 store visibilities (WRITE_SIZE 1.5->52MB). KEEP R16's
//   workspace re-layout (fixed 43MB + time-multiplexed scratch; wc in place
//   of g; 92KB/Nc -> Nc doubles, chunk dispatches halve).
// R15 (kept): reassociated attention (no 237-GFLOP xo@Wpkv GEMM).
// R14 (kept): 8 blocks/head co-located per XCD; qselT 128x64 tile.
// R13 (kept): gemm staging via global_load_lds + both-sides XOR swizzle.
// R12 (kept): all GEMM operands pre-converted bf16 [n][k]; x1b transposed.
// R11 (kept): landmarks qT slice in registers. R10: packed-u64 sync.
// R9: 8 blocks/head f64 dots. R8: transposed qT. R7: threefry idx0.

using u16 = unsigned short;
using u32 = unsigned int;
using u64 = unsigned long long;

typedef short bf16x8 __attribute__((ext_vector_type(8)));
typedef float f32x4 __attribute__((ext_vector_type(4)));

#define N_ 3136
#define C_ 768
#define H_ 12
#define F_ 16
#define P_ 196
#define L_ 128
#define SC_ 0.35355339059327373f   // 64^-0.25
#define OUTPART_ ((size_t)2 * N_ * C_)
#define KB_ 8                      // blocks per head in landmarks
#define RPB_ 392                   // rows per block (3136/8)

__device__ __forceinline__ float b2f(u16 u) {
  u32 x = ((u32)u) << 16; float f; __builtin_memcpy(&f, &x, 4); return f;
}
__device__ __forceinline__ float lo16f(u32 u) {
  u32 x = u << 16; float f; __builtin_memcpy(&f, &x, 4); return f;
}
__device__ __forceinline__ float hi16f(u32 u) {
  u32 x = u & 0xFFFF0000u; float f; __builtin_memcpy(&f, &x, 4); return f;
}
__device__ __forceinline__ u16 f2b(float f) {
  u32 u; __builtin_memcpy(&u, &f, 4);
  u32 r = (u + 0x7FFFu + ((u >> 16) & 1u)) >> 16;
  return (u16)r;
}
__device__ __forceinline__ u64 d2u(double d) { u64 u; __builtin_memcpy(&u, &d, 8); return u; }

// direct global->LDS DMA, 16B per lane; lds base must be wave-uniform.
__device__ __forceinline__ void gll16(const void* g, void* l) {
  __builtin_amdgcn_global_load_lds(
      (__attribute__((address_space(1))) void*)g,
      (__attribute__((address_space(3))) void*)l, 16, 0, 0);
}

// dtype sniffer (bf16 vs f32 inputs) — votes f32 on this dataset (proven R4)
__global__ void detect_k(const u32* __restrict__ w, int* __restrict__ flag) {
  const int t = threadIdx.x;  // 64
  int hits = 0;
  #pragma unroll
  for (int i = 0; i < 16; ++i) {
    u32 word = w[t * 16 + i];
    u32 e = (word >> 7) & 0xFFu;
    if (e >= 110u && e <= 126u) hits++;
  }
  #pragma unroll
  for (int off = 32; off > 0; off >>= 1) hits += __shfl_down(hits, off);
  if (t == 0) flag[0] = (hits >= 512) ? 0 : 1;  // 0=bf16, 1=f32
}

// zero candidate slots (24 heads x 2 parity x 8 blocks = 384 u64).
__global__ void zcnt_k(u64* __restrict__ p) { if (threadIdx.x < 384) p[threadIdx.x] = 0ull; }

// ---- exact JAX threefry2x32-20 core ----
__device__ __forceinline__ void tf2(u32 k0, u32 k1v, u32 c0, u32 c1, u32& o0, u32& o1) {
  u32 ks[3] = {k0, k1v, k0 ^ k1v ^ 0x1BD11BDAu};
  u32 x0 = c0 + ks[0], x1 = c1 + ks[1];
  const u32 rA[4] = {13u, 15u, 26u, 6u}, rB[4] = {17u, 29u, 16u, 24u};
  #pragma unroll
  for (int r = 0; r < 5; ++r) {
    #pragma unroll
    for (int q = 0; q < 4; ++q) {
      u32 rot = (r & 1) ? rB[q] : rA[q];
      x0 += x1; x1 = (x1 << rot) | (x1 >> (32u - rot)); x1 ^= x0;
    }
    x0 += ks[(r + 1) % 3];
    x1 += ks[(r + 2) % 3] + (u32)(r + 1);
  }
  o0 = x0; o1 = x1;
}

// jax.random.randint(key(42), (24,), 0, 3136), partitionable — PROVEN (R7).
__device__ __forceinline__ int tf_idx0(int bh) {
  u32 a0, a1, b0, b1;
  tf2(0u, 42u, 0u, 0u, a0, a1);
  tf2(0u, 42u, 0u, 1u, b0, b1);
  u32 j = (u32)bh;
  u32 h0, h1, l0, l1;
  tf2(a0, a1, 0u, j, h0, h1);
  u32 hi = h0 ^ h1;
  tf2(b0, b1, 0u, j, l0, l1);
  u32 lo = l0 ^ l1;
  return (int)(((hi % 3136u) * 2048u + (lo % 3136u)) % 3136u);
}

// ---------------- selection-grade f32 GEMM -> TRANSPOSED qT[bh][d][n] ----------------
__global__ __launch_bounds__(256) void qselT_k(const void* __restrict__ xr, const void* __restrict__ wr,
                                               const int* __restrict__ flagp, float* __restrict__ qt)
{
  __shared__ float As[128 * 20];
  __shared__ float Bs[16 * 64];
  const int t = threadIdx.x;
  const int m0 = blockIdx.x * 128;
  const int n0 = blockIdx.y * 64;
  const int f32i = flagp[0];
  const int tx = t & 15, ty = t >> 4;
  float acc[8][4];
  #pragma unroll
  for (int i = 0; i < 8; ++i)
    #pragma unroll
    for (int j = 0; j < 4; ++j) acc[i][j] = 0.f;

  const int alr = t >> 1;               // A tile row (0..127)
  const int alk = (t & 1) * 8;          // A k offset (0 or 8)
  const int bkr = t >> 4;               // B k row (0..15)
  const int bnc = (t & 15) * 4;         // B col offset

  for (int k0 = 0; k0 < 768; k0 += 16) {
    float av[8];
    float4 bv;
    if (f32i) {
      const float* xa = (const float*)xr + (size_t)(m0 + alr) * 768 + k0 + alk;
      float4 a0 = *(const float4*)(xa);
      float4 a1 = *(const float4*)(xa + 4);
      av[0] = a0.x; av[1] = a0.y; av[2] = a0.z; av[3] = a0.w;
      av[4] = a1.x; av[5] = a1.y; av[6] = a1.z; av[7] = a1.w;
      bv = *(const float4*)((const float*)wr + (size_t)(k0 + bkr) * 2304 + n0 + bnc);
    } else {
      const u16* xa = (const u16*)xr + (size_t)(m0 + alr) * 768 + k0 + alk;
      #pragma unroll
      for (int j = 0; j < 8; ++j) av[j] = b2f(xa[j]);
      const u16* wa = (const u16*)wr + (size_t)(k0 + bkr) * 2304 + n0 + bnc;
      bv.x = b2f(wa[0]); bv.y = b2f(wa[1]); bv.z = b2f(wa[2]); bv.w = b2f(wa[3]);
    }
    #pragma unroll
    for (int j = 0; j < 8; ++j) As[alr * 20 + alk + j] = av[j];
    *(float4*)(&Bs[bkr * 64 + bnc]) = bv;
    __syncthreads();
    #pragma unroll
    for (int kk = 0; kk < 16; ++kk) {
      float a[8], b[4];
      #pragma unroll
      for (int i = 0; i < 8; ++i) a[i] = As[(ty * 8 + i) * 20 + kk];
      #pragma unroll
      for (int j = 0; j < 4; ++j) b[j] = Bs[kk * 64 + tx * 4 + j];
      #pragma unroll
      for (int i = 0; i < 8; ++i)
        #pragma unroll
        for (int j = 0; j < 4; ++j) acc[i][j] += a[i] * b[j];
    }
    __syncthreads();
  }
  #pragma unroll
  for (int i = 0; i < 8; ++i) {
    const int m = m0 + ty * 8 + i;
    const int b = m / N_, n = m - b * N_;
    #pragma unroll
    for (int j = 0; j < 4; ++j) {
      const int col = n0 + tx * 4 + j;
      const int hh = col >> 6, dd = col & 63;
      qt[((size_t)(b * H_ + hh) * 64 + dd) * N_ + n] = acc[i][j] * SC_;
    }
  }
}

// ---------------- greedy landmarks: 8 blocks/head (same XCD), register-resident slice ----
// R15-proven version: one packed u64 candidate per block per step; winner
// column gathered from read-only qT; winner norm recomputed via butterfly.
__global__ __launch_bounds__(512, 1) void landmarksR_k(
    const float* __restrict__ qt, float* __restrict__ lm, u64* __restrict__ cand)
{
  const int kb = blockIdx.y;   // grid (24, KB_): all 8 blocks of a head on one XCD
  const int bh = blockIdx.x;
  const float* QT = qt + (size_t)bh * 64 * N_;   // [d][n]
  float* LM = lm + (size_t)bh * L_ * 64;
  u64* cd = cand + (size_t)bh * 16;
  __shared__ double curD[64];
  __shared__ u64 redV[8];
  __shared__ int redI[8];
  __shared__ int sW;
  const int t = threadIdx.x;
  const bool act = (t < RPB_);
  const int g = t >> 2, dc = t & 3, d0 = dc * 16;
  const int r0 = kb * RPB_;
  const int myRow = r0 + t;
  const float* base = QT + r0 + 4 * g;

  float4 qreg[16];
  #pragma unroll
  for (int i = 0; i < 16; ++i) qreg[i] = (float4){0.f, 0.f, 0.f, 0.f};
  if (act) {
    #pragma unroll
    for (int i = 0; i < 16; ++i) qreg[i] = *(const float4*)(base + (size_t)(d0 + i) * N_);
  }

  double inv_own = 0.0, ms_own = 0.0;
  if (act) {
    double s0 = 0.0, s1 = 0.0, s2 = 0.0, s3 = 0.0;
    #pragma unroll
    for (int i = 0; i < 16; ++i) {
      const float4 v = qreg[i];
      s0 += (double)v.x * (double)v.x; s1 += (double)v.y * (double)v.y;
      s2 += (double)v.z * (double)v.z; s3 += (double)v.w * (double)v.w;
    }
    s0 += __shfl_xor(s0, 1); s1 += __shfl_xor(s1, 1);
    s2 += __shfl_xor(s2, 1); s3 += __shfl_xor(s3, 1);
    s0 += __shfl_xor(s0, 2); s1 += __shfl_xor(s1, 2);
    s2 += __shfl_xor(s2, 2); s3 += __shfl_xor(s3, 2);
    const double sown = (dc == 0) ? s0 : (dc == 1) ? s1 : (dc == 2) ? s2 : s3;
    inv_own = 1.0 / fmax(sqrt(sown), 1e-12);
  }
  const int idx0 = tf_idx0(bh);
  if (act && myRow == idx0) ms_own = 10.0;

  if (t < 64) {
    const float vf = QT[(size_t)t * N_ + idx0];
    double v = (double)vf;
    double s = v * v;
    #pragma unroll
    for (int off = 32; off; off >>= 1) s += __shfl_xor(s, off);
    curD[t] = v / fmax(sqrt(s), 1e-12);
    if (kb == 0) LM[t] = vf;
  }
  __syncthreads();

  for (int step = 1; step < 128; ++step) {
    u64 bV = d2u(1e30); int bI = 0x7fffffff;
    if (act) {
      double a0 = 0.0, a1 = 0.0, a2 = 0.0, a3 = 0.0;
      #pragma unroll
      for (int i = 0; i < 16; ++i) {
        const float4 v = qreg[i];
        const double c = curD[d0 + i];
        a0 += (double)v.x * c; a1 += (double)v.y * c;
        a2 += (double)v.z * c; a3 += (double)v.w * c;
      }
      a0 += __shfl_xor(a0, 1); a1 += __shfl_xor(a1, 1);
      a2 += __shfl_xor(a2, 1); a3 += __shfl_xor(a3, 1);
      a0 += __shfl_xor(a0, 2); a1 += __shfl_xor(a1, 2);
      a2 += __shfl_xor(a2, 2); a3 += __shfl_xor(a3, 2);
      const double aown = (dc == 0) ? a0 : (dc == 1) ? a1 : (dc == 2) ? a2 : a3;
      ms_own = fmax(ms_own, fabs(aown * inv_own));
      bV = d2u(ms_own); bI = myRow;
    }
    #pragma unroll
    for (int off = 32; off; off >>= 1) {
      const u64 ov = __shfl_xor(bV, off);
      const int oi = __shfl_xor(bI, off);
      if (ov < bV || (ov == bV && oi < bI)) { bV = ov; bI = oi; }
    }
    if ((t & 63) == 0) { redV[t >> 6] = bV; redI[t >> 6] = bI; }
    __syncthreads();
    const int par = step & 1;
    if (t == 0) {
      u64 v = redV[0]; int ix = redI[0];
      #pragma unroll
      for (int w2 = 1; w2 < 8; ++w2)
        if (redV[w2] < v || (redV[w2] == v && redI[w2] < ix)) { v = redV[w2]; ix = redI[w2]; }
      const u64 pk = (v & ~((1ull << 19) - 1ull)) | ((u64)(u32)(step & 127) << 12) | (u64)(u32)ix;
      __hip_atomic_store(&cd[par * KB_ + kb], pk, __ATOMIC_RELAXED, __HIP_MEMORY_SCOPE_AGENT);
    }
    if (t < 64) {
      u64 pv = ~0ull;
      int ok = 1;
      for (;;) {
        if (t < KB_) {
          pv = __hip_atomic_load(&cd[par * KB_ + t], __ATOMIC_RELAXED, __HIP_MEMORY_SCOPE_AGENT);
          ok = ((int)((pv >> 12) & 127u) == step) ? 1 : 0;
        }
        if (__all(ok)) break;
        __builtin_amdgcn_s_sleep(1);
      }
      u64 m = (t < KB_) ? pv : ~0ull;
      #pragma unroll
      for (int off = 1; off < KB_; off <<= 1) {
        const u64 o = __shfl_xor(m, off);
        if (o < m) m = o;
      }
      if (t == 0) sW = (int)(m & 0xFFFu);
    }
    __syncthreads();
    const int w = sW;
    if (act && myRow == w) ms_own = 10.0;
    if (t < 64) {
      const float vf = QT[(size_t)t * N_ + w];
      double v = (double)vf;
      double s = v * v;
      #pragma unroll
      for (int off = 32; off; off >>= 1) s += __shfl_xor(s, off);
      curD[t] = v / fmax(sqrt(s), 1e-12);
      if (kb == 0) LM[(size_t)step * 64 + t] = vf;
    }
    __syncthreads();
  }
}

// ---------------- weight transpose + bf16-ify: W[K][Nn] raw -> WT[Nn][K] bf16 ----------------
__device__ __forceinline__ void twT_body(const void* W, int K, int Nn, int f32i,
                                         u16* WT, int k0, int n0, int t, u16 (&Ts)[64][80])
{
  const int kr = t >> 2, nc = (t & 3) * 16;
  u16 tmp[16];
  if (f32i) {
    const float* p = (const float*)W + (size_t)(k0 + kr) * Nn + n0 + nc;
    #pragma unroll
    for (int j = 0; j < 16; ++j) tmp[j] = f2b(p[j]);
  } else {
    const u16* p = (const u16*)W + (size_t)(k0 + kr) * Nn + n0 + nc;
    #pragma unroll
    for (int j = 0; j < 16; ++j) tmp[j] = p[j];
  }
  #pragma unroll
  for (int j = 0; j < 16; ++j) Ts[kr][nc + j] = tmp[j];
  __syncthreads();
  const int nr = t >> 2, kc = (t & 3) * 16;
  u16 o[16];
  #pragma unroll
  for (int j = 0; j < 16; ++j) o[j] = Ts[kc + j][nr];
  u16* dst = WT + (size_t)(n0 + nr) * K + k0 + kc;
  *(uint4*)(dst) = *(uint4*)(o);
  *(uint4*)(dst + 8) = *(uint4*)(o + 8);
}

__global__ __launch_bounds__(256) void twT_k(const void* __restrict__ W, int K, int Nn,
                                             const int* __restrict__ flagp, u16* __restrict__ WT)
{
  __shared__ u16 Ts[64][80];
  twT_body(W, K, Nn, flagp[0], WT, blockIdx.x * 64, blockIdx.y * 64, threadIdx.x, Ts);
}

// merged: z=0 Wpkv^T, z=1 Wpq^T, z=2 Wproj^T, z=3 Wpkv plain bf16 copy (original layout)
__global__ __launch_bounds__(256) void twT3_k(const void* __restrict__ W0, const void* __restrict__ W1,
                                              const void* __restrict__ W2, const int* __restrict__ flagp,
                                              u16* __restrict__ T0, u16* __restrict__ T1, u16* __restrict__ T2,
                                              u16* __restrict__ Wb)
{
  __shared__ u16 Ts[64][80];
  const int z = blockIdx.z;
  const int t = threadIdx.x;
  if (z == 3) {                       // plain convert Wpkv [768][1536] -> bf16
    const int k0 = blockIdx.x * 64, n0 = blockIdx.y * 64;
    const int kr = t >> 2, nc = (t & 3) * 16;
    u16 tmp[16];
    if (flagp[0]) {
      const float* p = (const float*)W0 + (size_t)(k0 + kr) * 1536 + n0 + nc;
      #pragma unroll
      for (int j = 0; j < 16; ++j) tmp[j] = f2b(p[j]);
    } else {
      const u16* p = (const u16*)W0 + (size_t)(k0 + kr) * 1536 + n0 + nc;
      #pragma unroll
      for (int j = 0; j < 16; ++j) tmp[j] = p[j];
    }
    u16* dst = Wb + (size_t)(k0 + kr) * 1536 + n0 + nc;
    *(uint4*)(dst) = *(uint4*)(tmp);
    *(uint4*)(dst + 8) = *(uint4*)(tmp + 8);
    return;
  }
  const void* W = (z == 0) ? W0 : (z == 1) ? W1 : W2;
  u16* WT = (z == 0) ? T0 : (z == 1) ? T1 : T2;
  const int Nn = (z == 0) ? 1536 : 768;
  if (blockIdx.y * 64 >= Nn) return;
  twT_body(W, 768, Nn, flagp[0], WT, blockIdx.x * 64, blockIdx.y * 64, t, Ts);
}

// ---------------- x -> bf16 (elementwise, 8/thread, 4816896 elems) ----------------
__global__ __launch_bounds__(256) void xcvt_k(const void* __restrict__ x,
                                              const int* __restrict__ flagp, u16* __restrict__ xb)
{
  const int i = blockIdx.x * 256 + threadIdx.x;  // 602112 threads exactly
  if (flagp[0]) {
    const float4* p = (const float4*)x + (size_t)i * 2;
    float4 f0 = p[0], f1 = p[1];
    u16 tmp[8] = { f2b(f0.x), f2b(f0.y), f2b(f0.z), f2b(f0.w),
                   f2b(f1.x), f2b(f1.y), f2b(f1.z), f2b(f1.w) };
    *(uint4*)(xb + (size_t)i * 8) = *(uint4*)tmp;
  } else {
    ((uint4*)xb)[i] = ((const uint4*)x)[i];
  }
}

// ---------------- shared GEMM core: global_load_lds staging + swizzled ds_read ----
struct GemmCore {
  const u16 *aP0, *aP1, *bP0, *bP1;
  u16 *lA0, *lA1, *lB0, *lB1;
  int roA[4], roB[4];
  int mw, nw, lr, lk;
};

__device__ __forceinline__ void gemm_core_init(GemmCore& gc, u16* As, u16* Bs,
    const u16* A16, const u16* B16, size_t aOff, size_t bOff,
    int m0, int n0, int lda, int ldb, int M, int t)
{
  const int lane = t & 63;
  const int w = t >> 6;
  gc.mw = (w >> 1) * 64;
  gc.nw = (w & 1) * 64;
  gc.lr = lane & 15;
  gc.lk = lane >> 4;
  const int c0 = w * 2, c1 = c0 + 1;
  const int rl = lane >> 2, sl = lane & 3;
  const int rowA0 = c0 * 16 + rl, rowA1 = c1 * 16 + rl;
  const int segA0 = (sl ^ ((rowA0 ^ (rowA0 >> 2)) & 3)) * 8;
  const int segA1 = (sl ^ ((rowA1 ^ (rowA1 >> 2)) & 3)) * 8;
  int ga0 = m0 + rowA0; if (ga0 >= M) ga0 = M - 1;
  int ga1 = m0 + rowA1; if (ga1 >= M) ga1 = M - 1;
  gc.aP0 = A16 + aOff + (size_t)ga0 * lda + segA0;
  gc.aP1 = A16 + aOff + (size_t)ga1 * lda + segA1;
  gc.bP0 = B16 + bOff + (size_t)(n0 + rowA0) * ldb + segA0;
  gc.bP1 = B16 + bOff + (size_t)(n0 + rowA1) * ldb + segA1;
  gc.lA0 = &As[c0 * 512]; gc.lA1 = &As[c1 * 512];
  gc.lB0 = &Bs[c0 * 512]; gc.lB1 = &Bs[c1 * 512];
  #pragma unroll
  for (int q = 0; q < 4; ++q) {
    const int ra = gc.mw + q * 16 + gc.lr;
    gc.roA[q] = ra * 32 + ((gc.lk ^ ((ra ^ (ra >> 2)) & 3)) * 8);
    const int rb = gc.nw + q * 16 + gc.lr;
    gc.roB[q] = rb * 32 + ((gc.lk ^ ((rb ^ (rb >> 2)) & 3)) * 8);
  }
}

__device__ __forceinline__ void gemm_core_loop(const GemmCore& gc, u16* As, u16* Bs,
                                               int K, f32x4 (&acc)[4][4])
{
  for (int k0 = 0; k0 < K; k0 += 32) {
    gll16(gc.aP0 + k0, gc.lA0);
    gll16(gc.aP1 + k0, gc.lA1);
    gll16(gc.bP0 + k0, gc.lB0);
    gll16(gc.bP1 + k0, gc.lB1);
    __syncthreads();
    bf16x8 af[4], bfv[4];
    #pragma unroll
    for (int mt = 0; mt < 4; ++mt) af[mt] = *(const bf16x8*)(&As[gc.roA[mt]]);
    #pragma unroll
    for (int nt = 0; nt < 4; ++nt) bfv[nt] = *(const bf16x8*)(&Bs[gc.roB[nt]]);
    #pragma unroll
    for (int mt = 0; mt < 4; ++mt)
      #pragma unroll
      for (int nt = 0; nt < 4; ++nt)
        acc[mt][nt] = __builtin_amdgcn_mfma_f32_16x16x32_bf16(af[mt], bfv[nt], acc[mt][nt], 0, 0, 0);
    __syncthreads();
  }
}

// ---------------- generic 128x128 bf16 MFMA GEMM, per-mode epilogues ----
// MODE 0: qkv->qb,kb,vb | 1: xoc+xdc | 3: q2b | 4: final out | 5: g | 6: ob part
template <int MODE>
__global__ __launch_bounds__(256) void gemm_k(
    const void* __restrict__ Ap, const void* __restrict__ Bp,
    int M, int K, int lda, int ldb, int n0c, int cn, const int* __restrict__ flagp,
    float* __restrict__ of0, u16* __restrict__ ob0, u16* __restrict__ ob1, u16* __restrict__ ob2,
    const void* __restrict__ biasRaw, void* __restrict__ outRaw)
{
  __shared__ u16 As[128 * 32];
  __shared__ u16 Bs[128 * 32];
  const int t = threadIdx.x;
  const int m0 = blockIdx.x * 128;
  const int n0 = blockIdx.y * 128;
  const int rf = (MODE == 4) ? flagp[0] : 0;

  size_t aOff = 0, bOff = 0;
  if constexpr (MODE == 1) {
    const int bh = blockIdx.z;
    aOff = (size_t)bh * ((size_t)N_ * 128) + (size_t)n0c * 128;
    bOff = (size_t)bh * (1024 * 128);
  }
  if constexpr (MODE == 5) {
    const int h = blockIdx.z;
    aOff = (size_t)h * (2 * cn) * 64;
    bOff = (size_t)h * 64;
  }
  if constexpr (MODE == 6) {
    const int h = blockIdx.z;
    aOff = (size_t)h * (2 * cn) * 768;
    bOff = (size_t)(768 + h * 64) * 768;
  }
  f32x4 acc[4][4];
  #pragma unroll
  for (int i = 0; i < 4; ++i)
    #pragma unroll
    for (int j = 0; j < 4; ++j) acc[i][j] = (f32x4){0.f, 0.f, 0.f, 0.f};

  GemmCore gc;
  gemm_core_init(gc, As, Bs, (const u16*)Ap, (const u16*)Bp, aOff, bOff, m0, n0, lda, ldb, M, t);
  gemm_core_loop(gc, As, Bs, K, acc);

  const int lr = gc.lr, lk = gc.lk, mw = gc.mw, nw = gc.nw;
  #pragma unroll
  for (int mt = 0; mt < 4; ++mt) {
    #pragma unroll
    for (int nt = 0; nt < 4; ++nt) {
      #pragma unroll
      for (int r = 0; r < 4; ++r) {
        const int grow = m0 + mw + mt * 16 + lk * 4 + r;
        const int gcol = n0 + nw + nt * 16 + lr;
        if (grow >= M) continue;
        float vv = acc[mt][nt][r];
        if constexpr (MODE == 0) {           // qkv -> qb,kb,vb bf16 (bh,N,64)
          int b = (grow >= N_) ? 1 : 0;
          int n = grow - b * N_;
          int t3 = gcol / C_, cc = gcol - t3 * C_;
          int hh = cc >> 6, dd = cc & 63;
          size_t dst = (((size_t)(b * H_ + hh)) * N_ + n) * 64 + dd;
          if (t3 == 0) ob0[dst] = f2b(vv * SC_);
          else if (t3 == 1) ob1[dst] = f2b(vv * SC_);
          else ob2[dst] = f2b(vv);
        } else if constexpr (MODE == 1) {    // xoc (B,cn,F,C) bf16 + xdiag side-write
          const int bh = blockIdx.z;
          int b = bh / H_, hh = bh - b * H_;
          int f = gcol >> 6, dd = gcol & 63;
          u16 wv = f2b(vv);
          ob0[(((size_t)(b * cn + grow)) * F_ + f) * C_ + hh * 64 + dd] = wv;
          int n = n0c + grow;
          if (f == n / P_) ob1[((size_t)(b * cn + grow)) * C_ + hh * 64 + dd] = wv;
        } else if constexpr (MODE == 3) {    // q2b [h][2cn][64] bf16, * 0.125
          int hh = gcol >> 6, dd = gcol & 63;
          ob0[((size_t)hh * (2 * cn) + grow) * 64 + dd] = f2b(vv * 0.125f);
        } else if constexpr (MODE == 5) {    // g [h][2cn][768] bf16
          ob0[((size_t)blockIdx.z * (2 * cn) + grow) * 768 + gcol] = f2b(vv);
        } else if constexpr (MODE == 6) {    // ob part: out_h = wc_h @ Wpkv_v_h
          if (gcol < 64) {
            int b2 = (grow >= cn) ? 1 : 0;
            int ln = grow - b2 * cn;
            ob0[((size_t)(b2 * N_ + n0c + ln)) * 768 + blockIdx.z * 64 + gcol] = f2b(vv);
          }
        } else {                             // MODE 4: out = o@W_proj + b_proj
          float bvad = rf ? ((const float*)biasRaw)[gcol] : b2f(((const u16*)biasRaw)[gcol]);
          float ov = vv + bvad;
          if (rf) ((float*)outRaw)[(size_t)grow * C_ + gcol] = ov;
          else    ((u16*)outRaw)[(size_t)grow * C_ + gcol] = f2b(ov);
        }
      }
    }
  }
}

// ---------------- kernel_1 = softmax_l(q . lm^T), bf16 out ----------------
__global__ __launch_bounds__(256) void k1_k(const u16* __restrict__ qb,
                                            const float* __restrict__ lm,
                                            u16* __restrict__ k1)
{
  const int bh = blockIdx.y;
  const int r0 = blockIdx.x * 64;
  __shared__ float qT[64][65];
  __shared__ float lmS[128 * 64];
  __shared__ float redA[4][64];
  __shared__ float redB[64];
  const int t = threadIdx.x;
  const u16* Q = qb + ((size_t)bh * N_ + r0) * 64;
  const float* Lm = lm + (size_t)bh * L_ * 64;
  for (int u = t; u < 2048; u += 256) ((float4*)lmS)[u] = ((const float4*)Lm)[u];
  for (int u = t; u < 512; u += 256) {
    int row = u >> 3, j0 = (u & 7) * 8;
    uint4 pk = *(const uint4*)(Q + (size_t)row * 64 + j0);
    const u16* pu = (const u16*)&pk;
    #pragma unroll
    for (int jj = 0; jj < 8; ++jj) qT[j0 + jj][row] = b2f(pu[jj]);
  }
  __syncthreads();
  const int row = t & 63, ch = t >> 6;
  float qr[64];
  #pragma unroll
  for (int j = 0; j < 64; ++j) qr[j] = qT[j][row];
  float s[32];
  for (int li = 0; li < 32; ++li) {
    const float* lp = lmS + (ch * 32 + li) * 64;
    float a = 0.f;
    #pragma unroll
    for (int j = 0; j < 64; ++j) a += lp[j] * qr[j];
    s[li] = a;
  }
  float mx = -1e30f;
  for (int li = 0; li < 32; ++li) mx = fmaxf(mx, s[li]);
  redA[ch][row] = mx;
  __syncthreads();
  if (t < 64) redB[t] = fmaxf(fmaxf(redA[0][t], redA[1][t]), fmaxf(redA[2][t], redA[3][t]));
  __syncthreads();
  mx = redB[row];
  float sum = 0.f;
  for (int li = 0; li < 32; ++li) { float e = __expf(s[li] - mx); s[li] = e; sum += e; }
  __syncthreads();
  redA[ch][row] = sum;
  __syncthreads();
  if (t < 64) redB[t] = 1.0f / (redA[0][t] + redA[1][t] + redA[2][t] + redA[3][t]);
  __syncthreads();
  const float inv = redB[row];
  u16* out = k1 + ((size_t)bh * N_ + r0 + row) * 128 + ch * 32;
  for (int li = 0; li < 32; ++li) out[li] = f2b(s[li] * inv);
}

// ---------------- kernel_2 per frame + x1 = kernel_2 @ v  (LDS-only, 3-pass) ----------------
// x1 written TRANSPOSED: x1T[bh][n = f*64+dd][l], coalesced per-u across lanes.
__global__ __launch_bounds__(256) void k2x1_k(const float* __restrict__ lm,
                                              const u16* __restrict__ kb,
                                              const u16* __restrict__ vb,
                                              u16* __restrict__ x1)
{
  const int bh = blockIdx.x;
  const int f = blockIdx.y;
  __shared__ u16 kS[P_ * 64];
  __shared__ u16 vS[P_ * 64];
  __shared__ float redM[2][128];
  __shared__ float redS[2][128];
  const int t = threadIdx.x;
  const u16* Kf = kb + ((size_t)bh * N_ + f * P_) * 64;
  const u16* Vf = vb + ((size_t)bh * N_ + f * P_) * 64;
  for (int u = t; u < 1568; u += 256) {
    ((uint4*)kS)[u] = ((const uint4*)Kf)[u];
    ((uint4*)vS)[u] = ((const uint4*)Vf)[u];
  }
  __syncthreads();
  const int l = t & 127, half = t >> 7;
  const float* lp = lm + ((size_t)bh * L_ + l) * 64;
  float lr[64];
  #pragma unroll
  for (int j = 0; j < 64; ++j) lr[j] = lp[j];

  const int p0 = half * 98, p1 = p0 + 98;
  float mx = -1e30f;
  for (int p = p0; p < p1; ++p) {
    const uint4* kp = (const uint4*)(kS + p * 64);
    float s = 0.f;
    #pragma unroll
    for (int q4 = 0; q4 < 8; ++q4) {
      uint4 pk = kp[q4];
      const u32* pu = (const u32*)&pk;
      #pragma unroll
      for (int j2 = 0; j2 < 4; ++j2) {
        u32 u = pu[j2];
        s += lr[q4 * 8 + j2 * 2] * lo16f(u) + lr[q4 * 8 + j2 * 2 + 1] * hi16f(u);
      }
    }
    mx = fmaxf(mx, s);
  }
  redM[half][l] = mx;
  __syncthreads();
  mx = fmaxf(redM[0][l], redM[1][l]);

  float sm = 0.f;
  for (int p = p0; p < p1; ++p) {
    const uint4* kp = (const uint4*)(kS + p * 64);
    float s = 0.f;
    #pragma unroll
    for (int q4 = 0; q4 < 8; ++q4) {
      uint4 pk = kp[q4];
      const u32* pu = (const u32*)&pk;
      #pragma unroll
      for (int j2 = 0; j2 < 4; ++j2) {
        u32 u = pu[j2];
        s += lr[q4 * 8 + j2 * 2] * lo16f(u) + lr[q4 * 8 + j2 * 2 + 1] * hi16f(u);
      }
    }
    sm += __expf(s - mx);
  }
  redS[half][l] = sm;
  __syncthreads();
  const float inv = 1.0f / (redS[0][l] + redS[1][l]);

  const int dd0 = half * 32;
  float acc[32];
  #pragma unroll
  for (int u = 0; u < 32; ++u) acc[u] = 0.f;
  for (int p = 0; p < P_; ++p) {
    const uint4* kp = (const uint4*)(kS + p * 64);
    float s = 0.f;
    #pragma unroll
    for (int q4 = 0; q4 < 8; ++q4) {
      uint4 pk = kp[q4];
      const u32* pu = (const u32*)&pk;
      #pragma unroll
      for (int j2 = 0; j2 < 4; ++j2) {
        u32 u = pu[j2];
        s += lr[q4 * 8 + j2 * 2] * lo16f(u) + lr[q4 * 8 + j2 * 2 + 1] * hi16f(u);
      }
    }
    const float e = __expf(s - mx);
    const uint4* vp = (const uint4*)(vS + p * 64 + dd0);
    #pragma unroll
    for (int q4 = 0; q4 < 4; ++q4) {
      uint4 pv = vp[q4];
      const u32* pu = (const u32*)&pv;
      #pragma unroll
      for (int j2 = 0; j2 < 4; ++j2) {
        u32 u = pu[j2];
        acc[q4 * 8 + j2 * 2]     += e * lo16f(u);
        acc[q4 * 8 + j2 * 2 + 1] += e * hi16f(u);
      }
    }
  }
  // transposed store: x1T[bh][f*64 + dd][l]; per-u the 128 l-lanes are contiguous
  u16* outT = x1 + (size_t)bh * (1024 * 128) + (size_t)(f * 64 + dd0) * 128 + l;
  for (int u = 0; u < 32; ++u) outT[(size_t)u * 128] = f2b(acc[u] * inv);
}

// ---------------- reassociated attention: logits = g.Xo, softmax, w = attn.Xo ----------------
// one block per token m=(b,ln). wc written IN PLACE of g (same indices; g row
// dead after phase 1; blocks touch only their own m row -> no cross hazard).
__global__ __launch_bounds__(256) void attn2_k(const u16* __restrict__ xoc,
                                               const u16* __restrict__ g,
                                               int n0c, int cn, const int* __restrict__ flagp,
                                               void* __restrict__ outRaw, u16* __restrict__ wc)
{
  __shared__ float aS[12][16];
  const int t = threadIdx.x;
  const int m = blockIdx.x;
  const int b = (m >= cn) ? 1 : 0;
  const int ln = m - b * cn;
  const int n = n0c + ln;
  const int f32o = flagp[0];
  const u16* Xo = xoc + ((size_t)(b * cn + ln) * 16) * 768;
  const size_t hstr = (size_t)(2 * cn) * 768;

  if (t < 192) {
    const int h = t >> 4, f = t & 15;
    const uint4* xp = (const uint4*)(Xo + (size_t)f * 768);
    const uint4* gp = (const uint4*)(g + (size_t)h * hstr + (size_t)m * 768);
    float lg = 0.f;
    #pragma unroll 4
    for (int q = 0; q < 96; ++q) {
      uint4 xv = xp[q], gv = gp[q];
      const u32* xu = (const u32*)&xv;
      const u32* gu = (const u32*)&gv;
      #pragma unroll
      for (int j = 0; j < 4; ++j)
        lg += lo16f(xu[j]) * lo16f(gu[j]) + hi16f(xu[j]) * hi16f(gu[j]);
    }
    float mx = lg;
    mx = fmaxf(mx, __shfl_xor(mx, 1));
    mx = fmaxf(mx, __shfl_xor(mx, 2));
    mx = fmaxf(mx, __shfl_xor(mx, 4));
    mx = fmaxf(mx, __shfl_xor(mx, 8));
    float e = __expf(lg - mx);
    float sm = e;
    sm += __shfl_xor(sm, 1);
    sm += __shfl_xor(sm, 2);
    sm += __shfl_xor(sm, 4);
    sm += __shfl_xor(sm, 8);
    const float a = e / sm;
    const size_t abase = ((size_t)(b * H_ + h) * N_ + n) * F_ + f;
    if (f32o) ((float*)outRaw)[OUTPART_ + abase] = a;
    else      ((u16*)outRaw)[OUTPART_ + abase] = f2b(a);
    aS[h][f] = a;
  }
  __syncthreads();
  if (t < 192) {
    const int cg = t >> 1, sh = t & 1;
    const int c0 = cg * 8;
    float acc[6][8];
    #pragma unroll
    for (int j = 0; j < 6; ++j)
      #pragma unroll
      for (int k = 0; k < 8; ++k) acc[j][k] = 0.f;
    for (int f = 0; f < 16; ++f) {
      uint4 xv = *(const uint4*)(Xo + (size_t)f * 768 + c0);
      const u32* xu = (const u32*)&xv;
      float xf[8];
      #pragma unroll
      for (int j = 0; j < 4; ++j) { xf[2 * j] = lo16f(xu[j]); xf[2 * j + 1] = hi16f(xu[j]); }
      #pragma unroll
      for (int j = 0; j < 6; ++j) {
        const float a = aS[sh * 6 + j][f];
        #pragma unroll
        for (int k = 0; k < 8; ++k) acc[j][k] += a * xf[k];
      }
    }
    #pragma unroll
    for (int j = 0; j < 6; ++j) {
      u16 pk[8];
      #pragma unroll
      for (int k = 0; k < 8; ++k) pk[k] = f2b(acc[j][k]);
      *(uint4*)(wc + (size_t)(sh * 6 + j) * hstr + (size_t)m * 768 + c0) = *(uint4*)pk;
    }
  }
}

extern "C" void kernel_launch(void* const* d_in, const int* in_sizes, int n_in,
                              void* d_out, int out_size, void* d_ws, size_t ws_size,
                              hipStream_t stream)
{
  (void)in_sizes; (void)n_in; (void)out_size;
  const void* x     = d_in[0];
  const void* Wqkv  = d_in[1];
  const void* Wpq   = d_in[2];
  const void* Wpkv  = d_in[3];
  const void* Wproj = d_in[4];
  const void* bproj = d_in[5];

  char* ws = (char*)d_ws;
  size_t off = 0;
  auto alloc = [&](size_t bytes) { void* p = ws + off; off += (bytes + 255) & ~(size_t)255; return p; };
  // ---- fixed region (live across the chunk loop) ----
  int*  flagp  = (int*)alloc(256);
  u16*  WpkvT  = (u16*)alloc(2359296);   // [1536][768] bf16
  u16*  WpqT   = (u16*)alloc(1179648);   // [768][768]
  u16*  WprojT = (u16*)alloc(1179648);   // [768][768]
  u16*  Wpkvb  = (u16*)alloc(2359296);   // [768][1536] bf16, original layout
  float* lm    = (float*)alloc(786432);  // (bh,128,64) f32
  u16*  x1b    = (u16*)alloc(6291456);   // (bh,1024,128) bf16 TRANSPOSED
  u16*  ob     = (u16*)alloc(9633792);   // (B,N,C) bf16
  u16*  k1b    = (u16*)alloc(19267584);  // (bh,N,128) bf16
  const size_t sc0 = off;                // scratch start (~43.1 MB)

  // ---- scratch overlays (time-multiplexed) ----
  // phase A (landmarks): qt 19.27MB + cand 3KB
  float* qt   = (float*)(ws + sc0);
  u64*   cand = (u64*)(ws + sc0 + 19267584);
  // phase B (projection): WqkvT 3.54 + xb 9.63 + qb/kbuf/vb 3x9.63 = 42.1MB
  u16* WqkvT = (u16*)(ws + sc0);
  u16* xb    = (u16*)(ws + sc0 + 3538944);
  u16* qb    = (u16*)(ws + sc0 + 13172736);
  u16* kbuf  = qb + 4816896;
  u16* vb    = kbuf + 4816896;
  // phase C (chunks): xoc + xdc + q2b + g(=wc in-place) = 46080 u16/Nc
  const size_t phaseB_need = sc0 + 42074112 + 1024;
  if (phaseB_need > ws_size) return;

  int Nc = 0;
  {
    const int cands[5] = {3136, 1568, 784, 392, 196};
    for (int i = 0; i < 5; ++i) {
      if (sc0 + (size_t)92160 * cands[i] + 1024 <= ws_size) { Nc = cands[i]; break; }
    }
  }
  if (Nc == 0) return;
  const int nchunks = N_ / Nc;
  u16* xoc = (u16*)(ws + sc0);            // (B,Nc,F,C) bf16
  u16* xdc = xoc + (size_t)24576 * Nc;    // (B,Nc,C) bf16
  u16* q2b = xdc + (size_t)1536 * Nc;     // [h][2Nc][64] bf16
  u16* gbf = q2b + (size_t)1536 * Nc;     // [h][2Nc][768] bf16; wc overwrites in place

  detect_k<<<1, 64, 0, stream>>>((const u32*)Wqkv, flagp);
  zcnt_k<<<1, 512, 0, stream>>>(cand);
  // weights to fixed region (independent of scratch) — run early
  twT3_k<<<dim3(12, 24, 4), 256, 0, stream>>>(Wpkv, Wpq, Wproj, flagp,
                                              WpkvT, WpqT, WprojT, Wpkvb);

  // selection-grade f32 qT (transposed), then fence-free multi-block landmarks
  qselT_k<<<dim3(49, 12), 256, 0, stream>>>(x, Wqkv, flagp, qt);
  landmarksR_k<<<dim3(24, KB_), 512, 0, stream>>>(qt, lm, cand);

  // qt dead: build bf16 operands in its place
  twT_k<<<dim3(12, 36), 256, 0, stream>>>(Wqkv, 768, 2304, flagp, WqkvT);
  xcvt_k<<<2352, 256, 0, stream>>>(x, flagp, xb);

  // qkv projection -> qb,kbuf,vb (global_load_lds staging)
  gemm_k<0><<<dim3(49, 18, 1), 256, 0, stream>>>(xb, WqkvT, 6272, 768, 768, 768, 0, 0, flagp,
                                                 nullptr, qb, kbuf, vb, nullptr, nullptr);
  // kernel_2 + x1 (LDS-only, transposed x1 out)
  k2x1_k<<<dim3(24, 16), 256, 0, stream>>>(lm, kbuf, vb, x1b);
  // kernel_1
  k1_k<<<dim3(49, 24), 256, 0, stream>>>(qb, lm, k1b);

  const int gx = (2 * Nc + 127) / 128;
  for (int c = 0; c < nchunks; ++c) {
    const int n0c = c * Nc;
    // xo = k1 @ x1 (+ xdiag side-write)
    gemm_k<1><<<dim3((Nc + 127) / 128, 8, 24), 256, 0, stream>>>(
        k1b, x1b, Nc, 128, 128, 128, n0c, Nc, flagp, nullptr, xoc, xdc, nullptr, nullptr, nullptr);
    // q2b = bf16(xdiag @ Wpq * 0.125), [h][2Nc][64]
    gemm_k<3><<<dim3(gx, 6, 1), 256, 0, stream>>>(
        xdc, WpqT, 2 * Nc, 768, 768, 768, n0c, Nc, flagp, nullptr, q2b, nullptr, nullptr, nullptr, nullptr);
    // g = bf16(q2b @ Wpkv_k^T), K=64, per-head
    gemm_k<5><<<dim3(gx, 6, 12), 256, 0, stream>>>(
        q2b, Wpkvb, 2 * Nc, 64, 64, 1536, n0c, Nc, flagp, nullptr, gbf, nullptr, nullptr, nullptr, nullptr);
    // logits = g.Xo -> softmax -> attn out + w = attn.Xo (wc in place of g)
    attn2_k<<<dim3(2 * Nc), 256, 0, stream>>>(xoc, gbf, n0c, Nc, flagp, d_out, gbf);
    // ob_h = wc_h @ Wpkv_v_h (N=64 masked)
    gemm_k<6><<<dim3(gx, 1, 12), 256, 0, stream>>>(
        gbf, WpkvT, 2 * Nc, 768, 768, 768, n0c, Nc, flagp, nullptr, ob, nullptr, nullptr, nullptr, nullptr);
  }
  // out = o @ W_proj + b_proj
  gemm_k<4><<<dim3(49, 6, 1), 256, 0, stream>>>(ob, WprojT, 6272, 768, 768, 768, 0, 0, flagp,
                                                nullptr, nullptr, nullptr, nullptr, bproj, d_out);
}

// Round 10
// 1482.727 us; speedup vs baseline: 1.3059x; 1.0263x over previous
//
#include <hip/hip_runtime.h>

// TrajectoryAttention on MI355X (gfx950), chunked pipeline, dtype-adaptive.
// R18: role-fused dispatches to fill the idle machine under latency-bound
//   phases (landmarks = 392us at <5% util):
//   fusedA = qselT || twT(WqkvT) || xcvt   (all independent, 256 thr roles)
//   fusedB = landmarksR(192 blocks, 512thr) || gemm0 qkv-projection tiles
//     (threads<256 run exact gemm_k<0> path; threads>=256 mirror the 48
//     __syncthreads). No-deadlock: gemm blocks never wait, so the 192
//     spinning landmark blocks always reach co-residency regardless of
//     dispatch order. Numerics of every role bit-identical to R17.
//   Memory: early phase needs 94.77MB concurrently (ws>=95.7 proven R8-era);
//   sequential R17 fallback if ws smaller. ob aliases dead qt in chunk phase.
// R17 (kept): R15-proven landmarksR packed-u64 barrier; R16 layout lessons.
// R15 (kept): reassociated attention (no 237-GFLOP xo@Wpkv GEMM).
// R14 (kept): 8 blocks/head co-located per XCD; qselT 128x64 tile.
// R13 (kept): gemm staging via global_load_lds + both-sides XOR swizzle.
// R12 (kept): all GEMM operands pre-converted bf16 [n][k]; x1b transposed.
// R11 (kept): landmarks qT slice in registers. R10: packed-u64 sync.
// R9: 8 blocks/head f64 dots. R8: transposed qT. R7: threefry idx0.

using u16 = unsigned short;
using u32 = unsigned int;
using u64 = unsigned long long;

typedef short bf16x8 __attribute__((ext_vector_type(8)));
typedef float f32x4 __attribute__((ext_vector_type(4)));

#define N_ 3136
#define C_ 768
#define H_ 12
#define F_ 16
#define P_ 196
#define L_ 128
#define SC_ 0.35355339059327373f   // 64^-0.25
#define OUTPART_ ((size_t)2 * N_ * C_)
#define KB_ 8                      // blocks per head in landmarks
#define RPB_ 392                   // rows per block (3136/8)

__device__ __forceinline__ float b2f(u16 u) {
  u32 x = ((u32)u) << 16; float f; __builtin_memcpy(&f, &x, 4); return f;
}
__device__ __forceinline__ float lo16f(u32 u) {
  u32 x = u << 16; float f; __builtin_memcpy(&f, &x, 4); return f;
}
__device__ __forceinline__ float hi16f(u32 u) {
  u32 x = u & 0xFFFF0000u; float f; __builtin_memcpy(&f, &x, 4); return f;
}
__device__ __forceinline__ u16 f2b(float f) {
  u32 u; __builtin_memcpy(&u, &f, 4);
  u32 r = (u + 0x7FFFu + ((u >> 16) & 1u)) >> 16;
  return (u16)r;
}
__device__ __forceinline__ u64 d2u(double d) { u64 u; __builtin_memcpy(&u, &d, 8); return u; }

// direct global->LDS DMA, 16B per lane; lds base must be wave-uniform.
__device__ __forceinline__ void gll16(const void* g, void* l) {
  __builtin_amdgcn_global_load_lds(
      (__attribute__((address_space(1))) void*)g,
      (__attribute__((address_space(3))) void*)l, 16, 0, 0);
}

// dtype sniffer (bf16 vs f32 inputs) — votes f32 on this dataset (proven R4)
__global__ void detect_k(const u32* __restrict__ w, int* __restrict__ flag) {
  const int t = threadIdx.x;  // 64
  int hits = 0;
  #pragma unroll
  for (int i = 0; i < 16; ++i) {
    u32 word = w[t * 16 + i];
    u32 e = (word >> 7) & 0xFFu;
    if (e >= 110u && e <= 126u) hits++;
  }
  #pragma unroll
  for (int off = 32; off > 0; off >>= 1) hits += __shfl_down(hits, off);
  if (t == 0) flag[0] = (hits >= 512) ? 0 : 1;  // 0=bf16, 1=f32
}

// zero candidate slots (24 heads x 2 parity x 8 blocks = 384 u64).
__global__ void zcnt_k(u64* __restrict__ p) { if (threadIdx.x < 384) p[threadIdx.x] = 0ull; }

// ---- exact JAX threefry2x32-20 core ----
__device__ __forceinline__ void tf2(u32 k0, u32 k1v, u32 c0, u32 c1, u32& o0, u32& o1) {
  u32 ks[3] = {k0, k1v, k0 ^ k1v ^ 0x1BD11BDAu};
  u32 x0 = c0 + ks[0], x1 = c1 + ks[1];
  const u32 rA[4] = {13u, 15u, 26u, 6u}, rB[4] = {17u, 29u, 16u, 24u};
  #pragma unroll
  for (int r = 0; r < 5; ++r) {
    #pragma unroll
    for (int q = 0; q < 4; ++q) {
      u32 rot = (r & 1) ? rB[q] : rA[q];
      x0 += x1; x1 = (x1 << rot) | (x1 >> (32u - rot)); x1 ^= x0;
    }
    x0 += ks[(r + 1) % 3];
    x1 += ks[(r + 2) % 3] + (u32)(r + 1);
  }
  o0 = x0; o1 = x1;
}

// jax.random.randint(key(42), (24,), 0, 3136), partitionable — PROVEN (R7).
__device__ __forceinline__ int tf_idx0(int bh) {
  u32 a0, a1, b0, b1;
  tf2(0u, 42u, 0u, 0u, a0, a1);
  tf2(0u, 42u, 0u, 1u, b0, b1);
  u32 j = (u32)bh;
  u32 h0, h1, l0, l1;
  tf2(a0, a1, 0u, j, h0, h1);
  u32 hi = h0 ^ h1;
  tf2(b0, b1, 0u, j, l0, l1);
  u32 lo = l0 ^ l1;
  return (int)(((hi % 3136u) * 2048u + (lo % 3136u)) % 3136u);
}

// ---------------- selection-grade f32 GEMM body -> TRANSPOSED qT[bh][d][n] ----------------
__device__ __forceinline__ void qsel_body(const void* xr, const void* wr, int f32i,
                                          float* qt, int m0, int n0, int t,
                                          float* As, float* Bs)
{
  const int tx = t & 15, ty = t >> 4;
  float acc[8][4];
  #pragma unroll
  for (int i = 0; i < 8; ++i)
    #pragma unroll
    for (int j = 0; j < 4; ++j) acc[i][j] = 0.f;

  const int alr = t >> 1;               // A tile row (0..127)
  const int alk = (t & 1) * 8;          // A k offset (0 or 8)
  const int bkr = t >> 4;               // B k row (0..15)
  const int bnc = (t & 15) * 4;         // B col offset

  for (int k0 = 0; k0 < 768; k0 += 16) {
    float av[8];
    float4 bv;
    if (f32i) {
      const float* xa = (const float*)xr + (size_t)(m0 + alr) * 768 + k0 + alk;
      float4 a0 = *(const float4*)(xa);
      float4 a1 = *(const float4*)(xa + 4);
      av[0] = a0.x; av[1] = a0.y; av[2] = a0.z; av[3] = a0.w;
      av[4] = a1.x; av[5] = a1.y; av[6] = a1.z; av[7] = a1.w;
      bv = *(const float4*)((const float*)wr + (size_t)(k0 + bkr) * 2304 + n0 + bnc);
    } else {
      const u16* xa = (const u16*)xr + (size_t)(m0 + alr) * 768 + k0 + alk;
      #pragma unroll
      for (int j = 0; j < 8; ++j) av[j] = b2f(xa[j]);
      const u16* wa = (const u16*)wr + (size_t)(k0 + bkr) * 2304 + n0 + bnc;
      bv.x = b2f(wa[0]); bv.y = b2f(wa[1]); bv.z = b2f(wa[2]); bv.w = b2f(wa[3]);
    }
    #pragma unroll
    for (int j = 0; j < 8; ++j) As[alr * 20 + alk + j] = av[j];
    *(float4*)(&Bs[bkr * 64 + bnc]) = bv;
    __syncthreads();
    #pragma unroll
    for (int kk = 0; kk < 16; ++kk) {
      float a[8], b[4];
      #pragma unroll
      for (int i = 0; i < 8; ++i) a[i] = As[(ty * 8 + i) * 20 + kk];
      #pragma unroll
      for (int j = 0; j < 4; ++j) b[j] = Bs[kk * 64 + tx * 4 + j];
      #pragma unroll
      for (int i = 0; i < 8; ++i)
        #pragma unroll
        for (int j = 0; j < 4; ++j) acc[i][j] += a[i] * b[j];
    }
    __syncthreads();
  }
  #pragma unroll
  for (int i = 0; i < 8; ++i) {
    const int m = m0 + ty * 8 + i;
    const int b = m / N_, n = m - b * N_;
    #pragma unroll
    for (int j = 0; j < 4; ++j) {
      const int col = n0 + tx * 4 + j;
      const int hh = col >> 6, dd = col & 63;
      qt[((size_t)(b * H_ + hh) * 64 + dd) * N_ + n] = acc[i][j] * SC_;
    }
  }
}

__global__ __launch_bounds__(256) void qselT_k(const void* __restrict__ xr, const void* __restrict__ wr,
                                               const int* __restrict__ flagp, float* __restrict__ qt)
{
  __shared__ float As[128 * 20];
  __shared__ float Bs[16 * 64];
  qsel_body(xr, wr, flagp[0], qt, blockIdx.x * 128, blockIdx.y * 64, threadIdx.x, As, Bs);
}

// ---------------- weight transpose + bf16-ify body ----------------
__device__ __forceinline__ void twT_body(const void* W, int K, int Nn, int f32i,
                                         u16* WT, int k0, int n0, int t, u16 (&Ts)[64][80])
{
  const int kr = t >> 2, nc = (t & 3) * 16;
  u16 tmp[16];
  if (f32i) {
    const float* p = (const float*)W + (size_t)(k0 + kr) * Nn + n0 + nc;
    #pragma unroll
    for (int j = 0; j < 16; ++j) tmp[j] = f2b(p[j]);
  } else {
    const u16* p = (const u16*)W + (size_t)(k0 + kr) * Nn + n0 + nc;
    #pragma unroll
    for (int j = 0; j < 16; ++j) tmp[j] = p[j];
  }
  #pragma unroll
  for (int j = 0; j < 16; ++j) Ts[kr][nc + j] = tmp[j];
  __syncthreads();
  const int nr = t >> 2, kc = (t & 3) * 16;
  u16 o[16];
  #pragma unroll
  for (int j = 0; j < 16; ++j) o[j] = Ts[kc + j][nr];
  u16* dst = WT + (size_t)(n0 + nr) * K + k0 + kc;
  *(uint4*)(dst) = *(uint4*)(o);
  *(uint4*)(dst + 8) = *(uint4*)(o + 8);
}

__global__ __launch_bounds__(256) void twT_k(const void* __restrict__ W, int K, int Nn,
                                             const int* __restrict__ flagp, u16* __restrict__ WT)
{
  __shared__ u16 Ts[64][80];
  twT_body(W, K, Nn, flagp[0], WT, blockIdx.x * 64, blockIdx.y * 64, threadIdx.x, Ts);
}

// merged: z=0 Wpkv^T, z=1 Wpq^T, z=2 Wproj^T, z=3 Wpkv plain bf16 copy (original layout)
__global__ __launch_bounds__(256) void twT3_k(const void* __restrict__ W0, const void* __restrict__ W1,
                                              const void* __restrict__ W2, const int* __restrict__ flagp,
                                              u16* __restrict__ T0, u16* __restrict__ T1, u16* __restrict__ T2,
                                              u16* __restrict__ Wb)
{
  __shared__ u16 Ts[64][80];
  const int z = blockIdx.z;
  const int t = threadIdx.x;
  if (z == 3) {                       // plain convert Wpkv [768][1536] -> bf16
    const int k0 = blockIdx.x * 64, n0 = blockIdx.y * 64;
    const int kr = t >> 2, nc = (t & 3) * 16;
    u16 tmp[16];
    if (flagp[0]) {
      const float* p = (const float*)W0 + (size_t)(k0 + kr) * 1536 + n0 + nc;
      #pragma unroll
      for (int j = 0; j < 16; ++j) tmp[j] = f2b(p[j]);
    } else {
      const u16* p = (const u16*)W0 + (size_t)(k0 + kr) * 1536 + n0 + nc;
      #pragma unroll
      for (int j = 0; j < 16; ++j) tmp[j] = p[j];
    }
    u16* dst = Wb + (size_t)(k0 + kr) * 1536 + n0 + nc;
    *(uint4*)(dst) = *(uint4*)(tmp);
    *(uint4*)(dst + 8) = *(uint4*)(tmp + 8);
    return;
  }
  const void* W = (z == 0) ? W0 : (z == 1) ? W1 : W2;
  u16* WT = (z == 0) ? T0 : (z == 1) ? T1 : T2;
  const int Nn = (z == 0) ? 1536 : 768;
  if (blockIdx.y * 64 >= Nn) return;
  twT_body(W, 768, Nn, flagp[0], WT, blockIdx.x * 64, blockIdx.y * 64, t, Ts);
}

// ---------------- x -> bf16 body (8 elems per thread-index i) ----------------
__device__ __forceinline__ void xcvt_body(const void* x, int f32i, u16* xb, int i)
{
  if (f32i) {
    const float4* p = (const float4*)x + (size_t)i * 2;
    float4 f0 = p[0], f1 = p[1];
    u16 tmp[8] = { f2b(f0.x), f2b(f0.y), f2b(f0.z), f2b(f0.w),
                   f2b(f1.x), f2b(f1.y), f2b(f1.z), f2b(f1.w) };
    *(uint4*)(xb + (size_t)i * 8) = *(uint4*)tmp;
  } else {
    ((uint4*)xb)[i] = ((const uint4*)x)[i];
  }
}

__global__ __launch_bounds__(256) void xcvt_k(const void* __restrict__ x,
                                              const int* __restrict__ flagp, u16* __restrict__ xb)
{
  xcvt_body(x, flagp[0], xb, blockIdx.x * 256 + threadIdx.x);
}

// ---------------- fusedA: qselT (588) || twT WqkvT (432) || xcvt (2352) ----------------
__global__ __launch_bounds__(256) void fusedA_k(const void* __restrict__ x, const void* __restrict__ Wqkv,
                                                const int* __restrict__ flagp, float* __restrict__ qt,
                                                u16* __restrict__ WqkvT, u16* __restrict__ xb)
{
  __shared__ float As[128 * 20];
  __shared__ float Bs[16 * 64];
  __shared__ u16 Ts[64][80];
  const int id = blockIdx.x;
  const int t = threadIdx.x;
  const int f32i = flagp[0];
  if (id < 588) {
    qsel_body(x, Wqkv, f32i, qt, (id % 49) * 128, (id / 49) * 64, t, As, Bs);
  } else if (id < 1020) {
    const int id2 = id - 588;
    twT_body(Wqkv, 768, 2304, f32i, WqkvT, (id2 % 12) * 64, (id2 / 12) * 64, t, Ts);
  } else {
    xcvt_body(x, f32i, xb, (id - 1020) * 256 + t);
  }
}

// ---------------- shared GEMM core: global_load_lds staging + swizzled ds_read ----
struct GemmCore {
  const u16 *aP0, *aP1, *bP0, *bP1;
  u16 *lA0, *lA1, *lB0, *lB1;
  int roA[4], roB[4];
  int mw, nw, lr, lk;
};

__device__ __forceinline__ void gemm_core_init(GemmCore& gc, u16* As, u16* Bs,
    const u16* A16, const u16* B16, size_t aOff, size_t bOff,
    int m0, int n0, int lda, int ldb, int M, int t)
{
  const int lane = t & 63;
  const int w = t >> 6;
  gc.mw = (w >> 1) * 64;
  gc.nw = (w & 1) * 64;
  gc.lr = lane & 15;
  gc.lk = lane >> 4;
  const int c0 = w * 2, c1 = c0 + 1;
  const int rl = lane >> 2, sl = lane & 3;
  const int rowA0 = c0 * 16 + rl, rowA1 = c1 * 16 + rl;
  const int segA0 = (sl ^ ((rowA0 ^ (rowA0 >> 2)) & 3)) * 8;
  const int segA1 = (sl ^ ((rowA1 ^ (rowA1 >> 2)) & 3)) * 8;
  int ga0 = m0 + rowA0; if (ga0 >= M) ga0 = M - 1;
  int ga1 = m0 + rowA1; if (ga1 >= M) ga1 = M - 1;
  gc.aP0 = A16 + aOff + (size_t)ga0 * lda + segA0;
  gc.aP1 = A16 + aOff + (size_t)ga1 * lda + segA1;
  gc.bP0 = B16 + bOff + (size_t)(n0 + rowA0) * ldb + segA0;
  gc.bP1 = B16 + bOff + (size_t)(n0 + rowA1) * ldb + segA1;
  gc.lA0 = &As[c0 * 512]; gc.lA1 = &As[c1 * 512];
  gc.lB0 = &Bs[c0 * 512]; gc.lB1 = &Bs[c1 * 512];
  #pragma unroll
  for (int q = 0; q < 4; ++q) {
    const int ra = gc.mw + q * 16 + gc.lr;
    gc.roA[q] = ra * 32 + ((gc.lk ^ ((ra ^ (ra >> 2)) & 3)) * 8);
    const int rb = gc.nw + q * 16 + gc.lr;
    gc.roB[q] = rb * 32 + ((gc.lk ^ ((rb ^ (rb >> 2)) & 3)) * 8);
  }
}

__device__ __forceinline__ void gemm_core_loop(const GemmCore& gc, u16* As, u16* Bs,
                                               int K, f32x4 (&acc)[4][4])
{
  for (int k0 = 0; k0 < K; k0 += 32) {
    gll16(gc.aP0 + k0, gc.lA0);
    gll16(gc.aP1 + k0, gc.lA1);
    gll16(gc.bP0 + k0, gc.lB0);
    gll16(gc.bP1 + k0, gc.lB1);
    __syncthreads();
    bf16x8 af[4], bfv[4];
    #pragma unroll
    for (int mt = 0; mt < 4; ++mt) af[mt] = *(const bf16x8*)(&As[gc.roA[mt]]);
    #pragma unroll
    for (int nt = 0; nt < 4; ++nt) bfv[nt] = *(const bf16x8*)(&Bs[gc.roB[nt]]);
    #pragma unroll
    for (int mt = 0; mt < 4; ++mt)
      #pragma unroll
      for (int nt = 0; nt < 4; ++nt)
        acc[mt][nt] = __builtin_amdgcn_mfma_f32_16x16x32_bf16(af[mt], bfv[nt], acc[mt][nt], 0, 0, 0);
    __syncthreads();
  }
}

// MODE0 epilogue: qkv -> qb,kb,vb bf16 (bh,N,64), q/k scaled
__device__ __forceinline__ void mode0_epi(const f32x4 (&acc)[4][4], int m0, int n0,
                                          int mw, int nw, int lr, int lk,
                                          u16* ob0, u16* ob1, u16* ob2)
{
  #pragma unroll
  for (int mt = 0; mt < 4; ++mt) {
    #pragma unroll
    for (int nt = 0; nt < 4; ++nt) {
      #pragma unroll
      for (int r = 0; r < 4; ++r) {
        const int grow = m0 + mw + mt * 16 + lk * 4 + r;
        const int gcol = n0 + nw + nt * 16 + lr;
        float vv = acc[mt][nt][r];
        int b = (grow >= N_) ? 1 : 0;
        int n = grow - b * N_;
        int t3 = gcol / C_, cc = gcol - t3 * C_;
        int hh = cc >> 6, dd = cc & 63;
        size_t dst = (((size_t)(b * H_ + hh)) * N_ + n) * 64 + dd;
        if (t3 == 0) ob0[dst] = f2b(vv * SC_);
        else if (t3 == 1) ob1[dst] = f2b(vv * SC_);
        else ob2[dst] = f2b(vv);
      }
    }
  }
}

// ---------------- fusedB: landmarksR (192 blocks, 512thr) || gemm0 (882 blocks) ----------------
// landmark flatten: bh = id%24, kb = id/24 -> XCD = id%8 = bh%8 (co-location kept).
__global__ __launch_bounds__(512, 1) void fusedB_k(
    const float* __restrict__ qt, float* __restrict__ lm, u64* __restrict__ cand,
    const u16* __restrict__ xb, const u16* __restrict__ WqkvT,
    u16* __restrict__ qb, u16* __restrict__ kbuf, u16* __restrict__ vb)
{
  __shared__ double curD[64];
  __shared__ u64 redV[8];
  __shared__ int redI[8];
  __shared__ int sW;
  __shared__ u16 As[128 * 32];
  __shared__ u16 Bs[128 * 32];
  const int t = threadIdx.x;

  if (blockIdx.x >= 192) {
    // ---- gemm0 role: exact gemm_k<0> path on threads <256; others mirror syncs ----
    const int gid = blockIdx.x - 192;
    const int m0 = (gid % 49) * 128;
    const int n0 = (gid / 49) * 128;
    if (t < 256) {
      f32x4 acc[4][4];
      #pragma unroll
      for (int i = 0; i < 4; ++i)
        #pragma unroll
        for (int j = 0; j < 4; ++j) acc[i][j] = (f32x4){0.f, 0.f, 0.f, 0.f};
      GemmCore gc;
      gemm_core_init(gc, As, Bs, xb, WqkvT, 0, 0, m0, n0, 768, 768, 6272, t);
      gemm_core_loop(gc, As, Bs, 768, acc);
      mode0_epi(acc, m0, n0, gc.mw, gc.nw, gc.lr, gc.lk, qb, kbuf, vb);
    } else {
      for (int i = 0; i < 24; ++i) { __syncthreads(); __syncthreads(); }
    }
    return;
  }

  // ---- landmarks role (R15/R17-proven body) ----
  const int bh = blockIdx.x % 24;
  const int kb = blockIdx.x / 24;
  const float* QT = qt + (size_t)bh * 64 * N_;   // [d][n]
  float* LM = lm + (size_t)bh * L_ * 64;
  u64* cd = cand + (size_t)bh * 16;
  const bool act = (t < RPB_);
  const int g = t >> 2, dc = t & 3, d0 = dc * 16;
  const int r0 = kb * RPB_;
  const int myRow = r0 + t;
  const float* base = QT + r0 + 4 * g;

  float4 qreg[16];
  #pragma unroll
  for (int i = 0; i < 16; ++i) qreg[i] = (float4){0.f, 0.f, 0.f, 0.f};
  if (act) {
    #pragma unroll
    for (int i = 0; i < 16; ++i) qreg[i] = *(const float4*)(base + (size_t)(d0 + i) * N_);
  }

  double inv_own = 0.0, ms_own = 0.0;
  if (act) {
    double s0 = 0.0, s1 = 0.0, s2 = 0.0, s3 = 0.0;
    #pragma unroll
    for (int i = 0; i < 16; ++i) {
      const float4 v = qreg[i];
      s0 += (double)v.x * (double)v.x; s1 += (double)v.y * (double)v.y;
      s2 += (double)v.z * (double)v.z; s3 += (double)v.w * (double)v.w;
    }
    s0 += __shfl_xor(s0, 1); s1 += __shfl_xor(s1, 1);
    s2 += __shfl_xor(s2, 1); s3 += __shfl_xor(s3, 1);
    s0 += __shfl_xor(s0, 2); s1 += __shfl_xor(s1, 2);
    s2 += __shfl_xor(s2, 2); s3 += __shfl_xor(s3, 2);
    const double sown = (dc == 0) ? s0 : (dc == 1) ? s1 : (dc == 2) ? s2 : s3;
    inv_own = 1.0 / fmax(sqrt(sown), 1e-12);
  }
  const int idx0 = tf_idx0(bh);
  if (act && myRow == idx0) ms_own = 10.0;

  if (t < 64) {
    const float vf = QT[(size_t)t * N_ + idx0];
    double v = (double)vf;
    double s = v * v;
    #pragma unroll
    for (int off = 32; off; off >>= 1) s += __shfl_xor(s, off);
    curD[t] = v / fmax(sqrt(s), 1e-12);
    if (kb == 0) LM[t] = vf;
  }
  __syncthreads();

  for (int step = 1; step < 128; ++step) {
    u64 bV = d2u(1e30); int bI = 0x7fffffff;
    if (act) {
      double a0 = 0.0, a1 = 0.0, a2 = 0.0, a3 = 0.0;
      #pragma unroll
      for (int i = 0; i < 16; ++i) {
        const float4 v = qreg[i];
        const double c = curD[d0 + i];
        a0 += (double)v.x * c; a1 += (double)v.y * c;
        a2 += (double)v.z * c; a3 += (double)v.w * c;
      }
      a0 += __shfl_xor(a0, 1); a1 += __shfl_xor(a1, 1);
      a2 += __shfl_xor(a2, 1); a3 += __shfl_xor(a3, 1);
      a0 += __shfl_xor(a0, 2); a1 += __shfl_xor(a1, 2);
      a2 += __shfl_xor(a2, 2); a3 += __shfl_xor(a3, 2);
      const double aown = (dc == 0) ? a0 : (dc == 1) ? a1 : (dc == 2) ? a2 : a3;
      ms_own = fmax(ms_own, fabs(aown * inv_own));
      bV = d2u(ms_own); bI = myRow;
    }
    #pragma unroll
    for (int off = 32; off; off >>= 1) {
      const u64 ov = __shfl_xor(bV, off);
      const int oi = __shfl_xor(bI, off);
      if (ov < bV || (ov == bV && oi < bI)) { bV = ov; bI = oi; }
    }
    if ((t & 63) == 0) { redV[t >> 6] = bV; redI[t >> 6] = bI; }
    __syncthreads();
    const int par = step & 1;
    if (t == 0) {
      u64 v = redV[0]; int ix = redI[0];
      #pragma unroll
      for (int w2 = 1; w2 < 8; ++w2)
        if (redV[w2] < v || (redV[w2] == v && redI[w2] < ix)) { v = redV[w2]; ix = redI[w2]; }
      const u64 pk = (v & ~((1ull << 19) - 1ull)) | ((u64)(u32)(step & 127) << 12) | (u64)(u32)ix;
      __hip_atomic_store(&cd[par * KB_ + kb], pk, __ATOMIC_RELAXED, __HIP_MEMORY_SCOPE_AGENT);
    }
    if (t < 64) {
      u64 pv = ~0ull;
      int ok = 1;
      for (;;) {
        if (t < KB_) {
          pv = __hip_atomic_load(&cd[par * KB_ + t], __ATOMIC_RELAXED, __HIP_MEMORY_SCOPE_AGENT);
          ok = ((int)((pv >> 12) & 127u) == step) ? 1 : 0;
        }
        if (__all(ok)) break;
        __builtin_amdgcn_s_sleep(1);
      }
      u64 m = (t < KB_) ? pv : ~0ull;
      #pragma unroll
      for (int off = 1; off < KB_; off <<= 1) {
        const u64 o = __shfl_xor(m, off);
        if (o < m) m = o;
      }
      if (t == 0) sW = (int)(m & 0xFFFu);
    }
    __syncthreads();
    const int w = sW;
    if (act && myRow == w) ms_own = 10.0;
    if (t < 64) {
      const float vf = QT[(size_t)t * N_ + w];
      double v = (double)vf;
      double s = v * v;
      #pragma unroll
      for (int off = 32; off; off >>= 1) s += __shfl_xor(s, off);
      curD[t] = v / fmax(sqrt(s), 1e-12);
      if (kb == 0) LM[(size_t)step * 64 + t] = vf;
    }
    __syncthreads();
  }
}

// ---------------- generic 128x128 bf16 MFMA GEMM, per-mode epilogues ----
// MODE 0: qkv->qb,kb,vb | 1: xoc+xdc | 3: q2b | 4: final out | 5: g | 6: ob part
template <int MODE>
__global__ __launch_bounds__(256) void gemm_k(
    const void* __restrict__ Ap, const void* __restrict__ Bp,
    int M, int K, int lda, int ldb, int n0c, int cn, const int* __restrict__ flagp,
    float* __restrict__ of0, u16* __restrict__ ob0, u16* __restrict__ ob1, u16* __restrict__ ob2,
    const void* __restrict__ biasRaw, void* __restrict__ outRaw)
{
  __shared__ u16 As[128 * 32];
  __shared__ u16 Bs[128 * 32];
  const int t = threadIdx.x;
  const int m0 = blockIdx.x * 128;
  const int n0 = blockIdx.y * 128;
  const int rf = (MODE == 4) ? flagp[0] : 0;

  size_t aOff = 0, bOff = 0;
  if constexpr (MODE == 1) {
    const int bh = blockIdx.z;
    aOff = (size_t)bh * ((size_t)N_ * 128) + (size_t)n0c * 128;
    bOff = (size_t)bh * (1024 * 128);
  }
  if constexpr (MODE == 5) {
    const int h = blockIdx.z;
    aOff = (size_t)h * (2 * cn) * 64;
    bOff = (size_t)h * 64;
  }
  if constexpr (MODE == 6) {
    const int h = blockIdx.z;
    aOff = (size_t)h * (2 * cn) * 768;
    bOff = (size_t)(768 + h * 64) * 768;
  }
  f32x4 acc[4][4];
  #pragma unroll
  for (int i = 0; i < 4; ++i)
    #pragma unroll
    for (int j = 0; j < 4; ++j) acc[i][j] = (f32x4){0.f, 0.f, 0.f, 0.f};

  GemmCore gc;
  gemm_core_init(gc, As, Bs, (const u16*)Ap, (const u16*)Bp, aOff, bOff, m0, n0, lda, ldb, M, t);
  gemm_core_loop(gc, As, Bs, K, acc);

  const int lr = gc.lr, lk = gc.lk, mw = gc.mw, nw = gc.nw;
  if constexpr (MODE == 0) {
    mode0_epi(acc, m0, n0, mw, nw, lr, lk, ob0, ob1, ob2);
    return;
  }
  #pragma unroll
  for (int mt = 0; mt < 4; ++mt) {
    #pragma unroll
    for (int nt = 0; nt < 4; ++nt) {
      #pragma unroll
      for (int r = 0; r < 4; ++r) {
        const int grow = m0 + mw + mt * 16 + lk * 4 + r;
        const int gcol = n0 + nw + nt * 16 + lr;
        if (grow >= M) continue;
        float vv = acc[mt][nt][r];
        if constexpr (MODE == 1) {           // xoc (B,cn,F,C) bf16 + xdiag side-write
          const int bh = blockIdx.z;
          int b = bh / H_, hh = bh - b * H_;
          int f = gcol >> 6, dd = gcol & 63;
          u16 wv = f2b(vv);
          ob0[(((size_t)(b * cn + grow)) * F_ + f) * C_ + hh * 64 + dd] = wv;
          int n = n0c + grow;
          if (f == n / P_) ob1[((size_t)(b * cn + grow)) * C_ + hh * 64 + dd] = wv;
        } else if constexpr (MODE == 3) {    // q2b [h][2cn][64] bf16, * 0.125
          int hh = gcol >> 6, dd = gcol & 63;
          ob0[((size_t)hh * (2 * cn) + grow) * 64 + dd] = f2b(vv * 0.125f);
        } else if constexpr (MODE == 5) {    // g [h][2cn][768] bf16
          ob0[((size_t)blockIdx.z * (2 * cn) + grow) * 768 + gcol] = f2b(vv);
        } else if constexpr (MODE == 6) {    // ob part: out_h = wc_h @ Wpkv_v_h
          if (gcol < 64) {
            int b2 = (grow >= cn) ? 1 : 0;
            int ln = grow - b2 * cn;
            ob0[((size_t)(b2 * N_ + n0c + ln)) * 768 + blockIdx.z * 64 + gcol] = f2b(vv);
          }
        } else {                             // MODE 4: out = o@W_proj + b_proj
          float bvad = rf ? ((const float*)biasRaw)[gcol] : b2f(((const u16*)biasRaw)[gcol]);
          float ov = vv + bvad;
          if (rf) ((float*)outRaw)[(size_t)grow * C_ + gcol] = ov;
          else    ((u16*)outRaw)[(size_t)grow * C_ + gcol] = f2b(ov);
        }
      }
    }
  }
}

// ---------------- kernel_1 = softmax_l(q . lm^T), bf16 out ----------------
__global__ __launch_bounds__(256) void k1_k(const u16* __restrict__ qb,
                                            const float* __restrict__ lm,
                                            u16* __restrict__ k1)
{
  const int bh = blockIdx.y;
  const int r0 = blockIdx.x * 64;
  __shared__ float qT[64][65];
  __shared__ float lmS[128 * 64];
  __shared__ float redA[4][64];
  __shared__ float redB[64];
  const int t = threadIdx.x;
  const u16* Q = qb + ((size_t)bh * N_ + r0) * 64;
  const float* Lm = lm + (size_t)bh * L_ * 64;
  for (int u = t; u < 2048; u += 256) ((float4*)lmS)[u] = ((const float4*)Lm)[u];
  for (int u = t; u < 512; u += 256) {
    int row = u >> 3, j0 = (u & 7) * 8;
    uint4 pk = *(const uint4*)(Q + (size_t)row * 64 + j0);
    const u16* pu = (const u16*)&pk;
    #pragma unroll
    for (int jj = 0; jj < 8; ++jj) qT[j0 + jj][row] = b2f(pu[jj]);
  }
  __syncthreads();
  const int row = t & 63, ch = t >> 6;
  float qr[64];
  #pragma unroll
  for (int j = 0; j < 64; ++j) qr[j] = qT[j][row];
  float s[32];
  for (int li = 0; li < 32; ++li) {
    const float* lp = lmS + (ch * 32 + li) * 64;
    float a = 0.f;
    #pragma unroll
    for (int j = 0; j < 64; ++j) a += lp[j] * qr[j];
    s[li] = a;
  }
  float mx = -1e30f;
  for (int li = 0; li < 32; ++li) mx = fmaxf(mx, s[li]);
  redA[ch][row] = mx;
  __syncthreads();
  if (t < 64) redB[t] = fmaxf(fmaxf(redA[0][t], redA[1][t]), fmaxf(redA[2][t], redA[3][t]));
  __syncthreads();
  mx = redB[row];
  float sum = 0.f;
  for (int li = 0; li < 32; ++li) { float e = __expf(s[li] - mx); s[li] = e; sum += e; }
  __syncthreads();
  redA[ch][row] = sum;
  __syncthreads();
  if (t < 64) redB[t] = 1.0f / (redA[0][t] + redA[1][t] + redA[2][t] + redA[3][t]);
  __syncthreads();
  const float inv = redB[row];
  u16* out = k1 + ((size_t)bh * N_ + r0 + row) * 128 + ch * 32;
  for (int li = 0; li < 32; ++li) out[li] = f2b(s[li] * inv);
}

// ---------------- kernel_2 per frame + x1 = kernel_2 @ v  (LDS-only, 3-pass) ----------------
// x1 written TRANSPOSED: x1T[bh][n = f*64+dd][l], coalesced per-u across lanes.
__global__ __launch_bounds__(256) void k2x1_k(const float* __restrict__ lm,
                                              const u16* __restrict__ kb,
                                              const u16* __restrict__ vb,
                                              u16* __restrict__ x1)
{
  const int bh = blockIdx.x;
  const int f = blockIdx.y;
  __shared__ u16 kS[P_ * 64];
  __shared__ u16 vS[P_ * 64];
  __shared__ float redM[2][128];
  __shared__ float redS[2][128];
  const int t = threadIdx.x;
  const u16* Kf = kb + ((size_t)bh * N_ + f * P_) * 64;
  const u16* Vf = vb + ((size_t)bh * N_ + f * P_) * 64;
  for (int u = t; u < 1568; u += 256) {
    ((uint4*)kS)[u] = ((const uint4*)Kf)[u];
    ((uint4*)vS)[u] = ((const uint4*)Vf)[u];
  }
  __syncthreads();
  const int l = t & 127, half = t >> 7;
  const float* lp = lm + ((size_t)bh * L_ + l) * 64;
  float lr[64];
  #pragma unroll
  for (int j = 0; j < 64; ++j) lr[j] = lp[j];

  const int p0 = half * 98, p1 = p0 + 98;
  float mx = -1e30f;
  for (int p = p0; p < p1; ++p) {
    const uint4* kp = (const uint4*)(kS + p * 64);
    float s = 0.f;
    #pragma unroll
    for (int q4 = 0; q4 < 8; ++q4) {
      uint4 pk = kp[q4];
      const u32* pu = (const u32*)&pk;
      #pragma unroll
      for (int j2 = 0; j2 < 4; ++j2) {
        u32 u = pu[j2];
        s += lr[q4 * 8 + j2 * 2] * lo16f(u) + lr[q4 * 8 + j2 * 2 + 1] * hi16f(u);
      }
    }
    mx = fmaxf(mx, s);
  }
  redM[half][l] = mx;
  __syncthreads();
  mx = fmaxf(redM[0][l], redM[1][l]);

  float sm = 0.f;
  for (int p = p0; p < p1; ++p) {
    const uint4* kp = (const uint4*)(kS + p * 64);
    float s = 0.f;
    #pragma unroll
    for (int q4 = 0; q4 < 8; ++q4) {
      uint4 pk = kp[q4];
      const u32* pu = (const u32*)&pk;
      #pragma unroll
      for (int j2 = 0; j2 < 4; ++j2) {
        u32 u = pu[j2];
        s += lr[q4 * 8 + j2 * 2] * lo16f(u) + lr[q4 * 8 + j2 * 2 + 1] * hi16f(u);
      }
    }
    sm += __expf(s - mx);
  }
  redS[half][l] = sm;
  __syncthreads();
  const float inv = 1.0f / (redS[0][l] + redS[1][l]);

  const int dd0 = half * 32;
  float acc[32];
  #pragma unroll
  for (int u = 0; u < 32; ++u) acc[u] = 0.f;
  for (int p = 0; p < P_; ++p) {
    const uint4* kp = (const uint4*)(kS + p * 64);
    float s = 0.f;
    #pragma unroll
    for (int q4 = 0; q4 < 8; ++q4) {
      uint4 pk = kp[q4];
      const u32* pu = (const u32*)&pk;
      #pragma unroll
      for (int j2 = 0; j2 < 4; ++j2) {
        u32 u = pu[j2];
        s += lr[q4 * 8 + j2 * 2] * lo16f(u) + lr[q4 * 8 + j2 * 2 + 1] * hi16f(u);
      }
    }
    const float e = __expf(s - mx);
    const uint4* vp = (const uint4*)(vS + p * 64 + dd0);
    #pragma unroll
    for (int q4 = 0; q4 < 4; ++q4) {
      uint4 pv = vp[q4];
      const u32* pu = (const u32*)&pv;
      #pragma unroll
      for (int j2 = 0; j2 < 4; ++j2) {
        u32 u = pu[j2];
        acc[q4 * 8 + j2 * 2]     += e * lo16f(u);
        acc[q4 * 8 + j2 * 2 + 1] += e * hi16f(u);
      }
    }
  }
  // transposed store: x1T[bh][f*64 + dd][l]; per-u the 128 l-lanes are contiguous
  u16* outT = x1 + (size_t)bh * (1024 * 128) + (size_t)(f * 64 + dd0) * 128 + l;
  for (int u = 0; u < 32; ++u) outT[(size_t)u * 128] = f2b(acc[u] * inv);
}

// ---------------- reassociated attention: logits = g.Xo, softmax, w = attn.Xo ----------------
// one block per token m=(b,ln). wc written IN PLACE of g (same indices; g row
// dead after phase 1; blocks touch only their own m row -> no cross hazard).
__global__ __launch_bounds__(256) void attn2_k(const u16* __restrict__ xoc,
                                               const u16* __restrict__ g,
                                               int n0c, int cn, const int* __restrict__ flagp,
                                               void* __restrict__ outRaw, u16* __restrict__ wc)
{
  __shared__ float aS[12][16];
  const int t = threadIdx.x;
  const int m = blockIdx.x;
  const int b = (m >= cn) ? 1 : 0;
  const int ln = m - b * cn;
  const int n = n0c + ln;
  const int f32o = flagp[0];
  const u16* Xo = xoc + ((size_t)(b * cn + ln) * 16) * 768;
  const size_t hstr = (size_t)(2 * cn) * 768;

  if (t < 192) {
    const int h = t >> 4, f = t & 15;
    const uint4* xp = (const uint4*)(Xo + (size_t)f * 768);
    const uint4* gp = (const uint4*)(g + (size_t)h * hstr + (size_t)m * 768);
    float lg = 0.f;
    #pragma unroll 4
    for (int q = 0; q < 96; ++q) {
      uint4 xv = xp[q], gv = gp[q];
      const u32* xu = (const u32*)&xv;
      const u32* gu = (const u32*)&gv;
      #pragma unroll
      for (int j = 0; j < 4; ++j)
        lg += lo16f(xu[j]) * lo16f(gu[j]) + hi16f(xu[j]) * hi16f(gu[j]);
    }
    float mx = lg;
    mx = fmaxf(mx, __shfl_xor(mx, 1));
    mx = fmaxf(mx, __shfl_xor(mx, 2));
    mx = fmaxf(mx, __shfl_xor(mx, 4));
    mx = fmaxf(mx, __shfl_xor(mx, 8));
    float e = __expf(lg - mx);
    float sm = e;
    sm += __shfl_xor(sm, 1);
    sm += __shfl_xor(sm, 2);
    sm += __shfl_xor(sm, 4);
    sm += __shfl_xor(sm, 8);
    const float a = e / sm;
    const size_t abase = ((size_t)(b * H_ + h) * N_ + n) * F_ + f;
    if (f32o) ((float*)outRaw)[OUTPART_ + abase] = a;
    else      ((u16*)outRaw)[OUTPART_ + abase] = f2b(a);
    aS[h][f] = a;
  }
  __syncthreads();
  if (t < 192) {
    const int cg = t >> 1, sh = t & 1;
    const int c0 = cg * 8;
    float acc[6][8];
    #pragma unroll
    for (int j = 0; j < 6; ++j)
      #pragma unroll
      for (int k = 0; k < 8; ++k) acc[j][k] = 0.f;
    for (int f = 0; f < 16; ++f) {
      uint4 xv = *(const uint4*)(Xo + (size_t)f * 768 + c0);
      const u32* xu = (const u32*)&xv;
      float xf[8];
      #pragma unroll
      for (int j = 0; j < 4; ++j) { xf[2 * j] = lo16f(xu[j]); xf[2 * j + 1] = hi16f(xu[j]); }
      #pragma unroll
      for (int j = 0; j < 6; ++j) {
        const float a = aS[sh * 6 + j][f];
        #pragma unroll
        for (int k = 0; k < 8; ++k) acc[j][k] += a * xf[k];
      }
    }
    #pragma unroll
    for (int j = 0; j < 6; ++j) {
      u16 pk[8];
      #pragma unroll
      for (int k = 0; k < 8; ++k) pk[k] = f2b(acc[j][k]);
      *(uint4*)(wc + (size_t)(sh * 6 + j) * hstr + (size_t)m * 768 + c0) = *(uint4*)pk;
    }
  }
}

extern "C" void kernel_launch(void* const* d_in, const int* in_sizes, int n_in,
                              void* d_out, int out_size, void* d_ws, size_t ws_size,
                              hipStream_t stream)
{
  (void)in_sizes; (void)n_in; (void)out_size;
  const void* x     = d_in[0];
  const void* Wqkv  = d_in[1];
  const void* Wpq   = d_in[2];
  const void* Wpkv  = d_in[3];
  const void* Wproj = d_in[4];
  const void* bproj = d_in[5];

  char* ws = (char*)d_ws;
  size_t off = 0;
  auto alloc = [&](size_t bytes) { void* p = ws + off; off += (bytes + 255) & ~(size_t)255; return p; };
  // ---- fixed region (live across the chunk loop) ----
  int*  flagp  = (int*)alloc(256);
  u16*  WpkvT  = (u16*)alloc(2359296);   // [1536][768] bf16
  u16*  WpqT   = (u16*)alloc(1179648);   // [768][768]
  u16*  WprojT = (u16*)alloc(1179648);   // [768][768]
  u16*  Wpkvb  = (u16*)alloc(2359296);   // [768][1536] bf16, original layout
  float* lm    = (float*)alloc(786432);  // (bh,128,64) f32
  u16*  x1b    = (u16*)alloc(6291456);   // (bh,1024,128) bf16 TRANSPOSED
  u16*  k1b    = (u16*)alloc(19267584);  // (bh,N,128) bf16
  const size_t sc0 = off;                // scratch start (~33.4 MB)

  // fused layout: [qt+cand][WqkvT+xb][qb+kbuf+vb] concurrently live
  const size_t r1 = sc0;
  const size_t r2 = r1 + 19267584 + 3072;
  const size_t r3 = r2 + 3538944 + 9633792;
  const size_t bigNeed = r3 + 3 * (size_t)9633792 + 256;
  const bool fused = (bigNeed <= ws_size);

  float* qt;  u64* cand;  u16 *WqkvT, *xb, *qb, *kbuf, *vb, *ob;
  size_t chunkBase;
  if (fused) {
    qt    = (float*)(ws + r1);
    cand  = (u64*)(ws + r1 + 19267584);
    WqkvT = (u16*)(ws + r2);
    xb    = WqkvT + 1769472;             // 3538944 B
    qb    = (u16*)(ws + r3);
    kbuf  = qb + 4816896;
    vb    = kbuf + 4816896;
    ob    = (u16*)(ws + sc0);            // alias qt (dead in chunk phase)
    chunkBase = sc0 + 9633792;
  } else {
    // sequential fallback (R17 layout): overlays
    qt    = (float*)(ws + sc0);
    cand  = (u64*)(ws + sc0 + 19267584);
    WqkvT = (u16*)(ws + sc0);
    xb    = (u16*)(ws + sc0 + 3538944);
    qb    = (u16*)(ws + sc0 + 13172736);
    kbuf  = qb + 4816896;
    vb    = kbuf + 4816896;
    ob    = (u16*)(ws + sc0);            // alias qt (dead in chunk phase)
    chunkBase = sc0 + 9633792;
    if (sc0 + 42074112 + 1024 > ws_size) return;
  }

  int Nc = 0;
  {
    const int cands[5] = {3136, 1568, 784, 392, 196};
    for (int i = 0; i < 5; ++i) {
      if (chunkBase + (size_t)92160 * cands[i] + 1024 <= ws_size) { Nc = cands[i]; break; }
    }
  }
  if (Nc == 0) return;
  const int nchunks = N_ / Nc;
  u16* xoc = (u16*)(ws + chunkBase);      // (B,Nc,F,C) bf16
  u16* xdc = xoc + (size_t)24576 * Nc;    // (B,Nc,C) bf16
  u16* q2b = xdc + (size_t)1536 * Nc;     // [h][2Nc][64] bf16
  u16* gbf = q2b + (size_t)1536 * Nc;     // [h][2Nc][768] bf16; wc overwrites in place

  detect_k<<<1, 64, 0, stream>>>((const u32*)Wqkv, flagp);
  zcnt_k<<<1, 512, 0, stream>>>(cand);
  // weights to fixed region — independent, run early
  twT3_k<<<dim3(12, 24, 4), 256, 0, stream>>>(Wpkv, Wpq, Wproj, flagp,
                                              WpkvT, WpqT, WprojT, Wpkvb);

  if (fused) {
    // qselT || twT(WqkvT) || xcvt  (independent roles)
    fusedA_k<<<3372, 256, 0, stream>>>(x, Wqkv, flagp, qt, WqkvT, xb);
    // landmarks || gemm0 (qkv projection)
    fusedB_k<<<1074, 512, 0, stream>>>(qt, lm, cand, xb, WqkvT, qb, kbuf, vb);
  } else {
    qselT_k<<<dim3(49, 12), 256, 0, stream>>>(x, Wqkv, flagp, qt);
    fusedB_k<<<192, 512, 0, stream>>>(qt, lm, cand, xb, WqkvT, qb, kbuf, vb);  // landmarks only
    twT_k<<<dim3(12, 36), 256, 0, stream>>>(Wqkv, 768, 2304, flagp, WqkvT);
    xcvt_k<<<2352, 256, 0, stream>>>(x, flagp, xb);
    gemm_k<0><<<dim3(49, 18, 1), 256, 0, stream>>>(xb, WqkvT, 6272, 768, 768, 768, 0, 0, flagp,
                                                   nullptr, qb, kbuf, vb, nullptr, nullptr);
  }

  // kernel_2 + x1 (LDS-only, transposed x1 out)
  k2x1_k<<<dim3(24, 16), 256, 0, stream>>>(lm, kbuf, vb, x1b);
  // kernel_1
  k1_k<<<dim3(49, 24), 256, 0, stream>>>(qb, lm, k1b);

  const int gx = (2 * Nc + 127) / 128;
  for (int c = 0; c < nchunks; ++c) {
    const int n0c = c * Nc;
    // xo = k1 @ x1 (+ xdiag side-write)
    gemm_k<1><<<dim3((Nc + 127) / 128, 8, 24), 256, 0, stream>>>(
        k1b, x1b, Nc, 128, 128, 128, n0c, Nc, flagp, nullptr, xoc, xdc, nullptr, nullptr, nullptr);
    // q2b = bf16(xdiag @ Wpq * 0.125), [h][2Nc][64]
    gemm_k<3><<<dim3(gx, 6, 1), 256, 0, stream>>>(
        xdc, WpqT, 2 * Nc, 768, 768, 768, n0c, Nc, flagp, nullptr, q2b, nullptr, nullptr, nullptr, nullptr);
    // g = bf16(q2b @ Wpkv_k^T), K=64, per-head
    gemm_k<5><<<dim3(gx, 6, 12), 256, 0, stream>>>(
        q2b, Wpkvb, 2 * Nc, 64, 64, 1536, n0c, Nc, flagp, nullptr, gbf, nullptr, nullptr, nullptr, nullptr);
    // logits = g.Xo -> softmax -> attn out + w = attn.Xo (wc in place of g)
    attn2_k<<<dim3(2 * Nc), 256, 0, stream>>>(xoc, gbf, n0c, Nc, flagp, d_out, gbf);
    // ob_h = wc_h @ Wpkv_v_h (N=64 masked)
    gemm_k<6><<<dim3(gx, 1, 12), 256, 0, stream>>>(
        gbf, WpkvT, 2 * Nc, 768, 768, 768, n0c, Nc, flagp, nullptr, ob, nullptr, nullptr, nullptr, nullptr);
  }
  // out = o @ W_proj + b_proj
  gemm_k<4><<<dim3(49, 6, 1), 256, 0, stream>>>(ob, WprojT, 6272, 768, 768, 768, 0, 0, flagp,
                                                nullptr, nullptr, nullptr, nullptr, bproj, d_out);
}

// Round 11
// 1462.655 us; speedup vs baseline: 1.3238x; 1.0137x over previous
//
#include <hip/hip_runtime.h>

// TrajectoryAttention on MI355X (gfx950), chunked pipeline, dtype-adaptive.
// R19: launch-structure round (zero numeric change):
//  (1) ob moved to END of ws (time-shares the dead qb/kbuf/vb tail) -> chunk
//      region starts at sc0: ~53MB on a 96MB ws -> Nc=448 (7 chunks), Nc=784
//      if ws>=116MB. Chunk dispatches drop 40->35 (or 20).
//  (2) fusedC = k2x1 || k1 (independent inputs; 52KB smem union, role-split
//      blocks). k2x1 alone left half the machine idle (384 blocks, 50KB LDS).
//  (3) fusedA also absorbs the twT3 weight-prep roles (1152 blocks).
// R18 (kept): fusedA = qselT||twT||xcvt; fusedB = landmarksR||gemm0.
// R17 (kept): R15-proven landmarksR packed-u64 barrier.
// R15 (kept): reassociated attention (no 237-GFLOP xo@Wpkv GEMM).
// R14 (kept): 8 blocks/head co-located per XCD. R13: global_load_lds + XOR
// swizzle. R12: bf16 [n][k] operands; x1b transposed. R11: qT in registers.
// R10: packed-u64 sync. R9: 8 blocks/head f64 dots. R8: transposed qT.
// R7: threefry idx0.

using u16 = unsigned short;
using u32 = unsigned int;
using u64 = unsigned long long;

typedef short bf16x8 __attribute__((ext_vector_type(8)));
typedef float f32x4 __attribute__((ext_vector_type(4)));

#define N_ 3136
#define C_ 768
#define H_ 12
#define F_ 16
#define P_ 196
#define L_ 128
#define SC_ 0.35355339059327373f   // 64^-0.25
#define OUTPART_ ((size_t)2 * N_ * C_)
#define KB_ 8                      // blocks per head in landmarks
#define RPB_ 392                   // rows per block (3136/8)

__device__ __forceinline__ float b2f(u16 u) {
  u32 x = ((u32)u) << 16; float f; __builtin_memcpy(&f, &x, 4); return f;
}
__device__ __forceinline__ float lo16f(u32 u) {
  u32 x = u << 16; float f; __builtin_memcpy(&f, &x, 4); return f;
}
__device__ __forceinline__ float hi16f(u32 u) {
  u32 x = u & 0xFFFF0000u; float f; __builtin_memcpy(&f, &x, 4); return f;
}
__device__ __forceinline__ u16 f2b(float f) {
  u32 u; __builtin_memcpy(&u, &f, 4);
  u32 r = (u + 0x7FFFu + ((u >> 16) & 1u)) >> 16;
  return (u16)r;
}
__device__ __forceinline__ u64 d2u(double d) { u64 u; __builtin_memcpy(&u, &d, 8); return u; }

// direct global->LDS DMA, 16B per lane; lds base must be wave-uniform.
__device__ __forceinline__ void gll16(const void* g, void* l) {
  __builtin_amdgcn_global_load_lds(
      (__attribute__((address_space(1))) void*)g,
      (__attribute__((address_space(3))) void*)l, 16, 0, 0);
}

// dtype sniffer (bf16 vs f32 inputs) — votes f32 on this dataset (proven R4)
__global__ void detect_k(const u32* __restrict__ w, int* __restrict__ flag) {
  const int t = threadIdx.x;  // 64
  int hits = 0;
  #pragma unroll
  for (int i = 0; i < 16; ++i) {
    u32 word = w[t * 16 + i];
    u32 e = (word >> 7) & 0xFFu;
    if (e >= 110u && e <= 126u) hits++;
  }
  #pragma unroll
  for (int off = 32; off > 0; off >>= 1) hits += __shfl_down(hits, off);
  if (t == 0) flag[0] = (hits >= 512) ? 0 : 1;  // 0=bf16, 1=f32
}

// zero candidate slots (24 heads x 2 parity x 8 blocks = 384 u64).
__global__ void zcnt_k(u64* __restrict__ p) { if (threadIdx.x < 384) p[threadIdx.x] = 0ull; }

// ---- exact JAX threefry2x32-20 core ----
__device__ __forceinline__ void tf2(u32 k0, u32 k1v, u32 c0, u32 c1, u32& o0, u32& o1) {
  u32 ks[3] = {k0, k1v, k0 ^ k1v ^ 0x1BD11BDAu};
  u32 x0 = c0 + ks[0], x1 = c1 + ks[1];
  const u32 rA[4] = {13u, 15u, 26u, 6u}, rB[4] = {17u, 29u, 16u, 24u};
  #pragma unroll
  for (int r = 0; r < 5; ++r) {
    #pragma unroll
    for (int q = 0; q < 4; ++q) {
      u32 rot = (r & 1) ? rB[q] : rA[q];
      x0 += x1; x1 = (x1 << rot) | (x1 >> (32u - rot)); x1 ^= x0;
    }
    x0 += ks[(r + 1) % 3];
    x1 += ks[(r + 2) % 3] + (u32)(r + 1);
  }
  o0 = x0; o1 = x1;
}

// jax.random.randint(key(42), (24,), 0, 3136), partitionable — PROVEN (R7).
__device__ __forceinline__ int tf_idx0(int bh) {
  u32 a0, a1, b0, b1;
  tf2(0u, 42u, 0u, 0u, a0, a1);
  tf2(0u, 42u, 0u, 1u, b0, b1);
  u32 j = (u32)bh;
  u32 h0, h1, l0, l1;
  tf2(a0, a1, 0u, j, h0, h1);
  u32 hi = h0 ^ h1;
  tf2(b0, b1, 0u, j, l0, l1);
  u32 lo = l0 ^ l1;
  return (int)(((hi % 3136u) * 2048u + (lo % 3136u)) % 3136u);
}

// ---------------- selection-grade f32 GEMM body -> TRANSPOSED qT[bh][d][n] ----------------
__device__ __forceinline__ void qsel_body(const void* xr, const void* wr, int f32i,
                                          float* qt, int m0, int n0, int t,
                                          float* As, float* Bs)
{
  const int tx = t & 15, ty = t >> 4;
  float acc[8][4];
  #pragma unroll
  for (int i = 0; i < 8; ++i)
    #pragma unroll
    for (int j = 0; j < 4; ++j) acc[i][j] = 0.f;

  const int alr = t >> 1;
  const int alk = (t & 1) * 8;
  const int bkr = t >> 4;
  const int bnc = (t & 15) * 4;

  for (int k0 = 0; k0 < 768; k0 += 16) {
    float av[8];
    float4 bv;
    if (f32i) {
      const float* xa = (const float*)xr + (size_t)(m0 + alr) * 768 + k0 + alk;
      float4 a0 = *(const float4*)(xa);
      float4 a1 = *(const float4*)(xa + 4);
      av[0] = a0.x; av[1] = a0.y; av[2] = a0.z; av[3] = a0.w;
      av[4] = a1.x; av[5] = a1.y; av[6] = a1.z; av[7] = a1.w;
      bv = *(const float4*)((const float*)wr + (size_t)(k0 + bkr) * 2304 + n0 + bnc);
    } else {
      const u16* xa = (const u16*)xr + (size_t)(m0 + alr) * 768 + k0 + alk;
      #pragma unroll
      for (int j = 0; j < 8; ++j) av[j] = b2f(xa[j]);
      const u16* wa = (const u16*)wr + (size_t)(k0 + bkr) * 2304 + n0 + bnc;
      bv.x = b2f(wa[0]); bv.y = b2f(wa[1]); bv.z = b2f(wa[2]); bv.w = b2f(wa[3]);
    }
    #pragma unroll
    for (int j = 0; j < 8; ++j) As[alr * 20 + alk + j] = av[j];
    *(float4*)(&Bs[bkr * 64 + bnc]) = bv;
    __syncthreads();
    #pragma unroll
    for (int kk = 0; kk < 16; ++kk) {
      float a[8], b[4];
      #pragma unroll
      for (int i = 0; i < 8; ++i) a[i] = As[(ty * 8 + i) * 20 + kk];
      #pragma unroll
      for (int j = 0; j < 4; ++j) b[j] = Bs[kk * 64 + tx * 4 + j];
      #pragma unroll
      for (int i = 0; i < 8; ++i)
        #pragma unroll
        for (int j = 0; j < 4; ++j) acc[i][j] += a[i] * b[j];
    }
    __syncthreads();
  }
  #pragma unroll
  for (int i = 0; i < 8; ++i) {
    const int m = m0 + ty * 8 + i;
    const int b = m / N_, n = m - b * N_;
    #pragma unroll
    for (int j = 0; j < 4; ++j) {
      const int col = n0 + tx * 4 + j;
      const int hh = col >> 6, dd = col & 63;
      qt[((size_t)(b * H_ + hh) * 64 + dd) * N_ + n] = acc[i][j] * SC_;
    }
  }
}

__global__ __launch_bounds__(256) void qselT_k(const void* __restrict__ xr, const void* __restrict__ wr,
                                               const int* __restrict__ flagp, float* __restrict__ qt)
{
  __shared__ float As[128 * 20];
  __shared__ float Bs[16 * 64];
  qsel_body(xr, wr, flagp[0], qt, blockIdx.x * 128, blockIdx.y * 64, threadIdx.x, As, Bs);
}

// ---------------- weight transpose + bf16-ify body ----------------
__device__ __forceinline__ void twT_body(const void* W, int K, int Nn, int f32i,
                                         u16* WT, int k0, int n0, int t, u16 (&Ts)[64][80])
{
  const int kr = t >> 2, nc = (t & 3) * 16;
  u16 tmp[16];
  if (f32i) {
    const float* p = (const float*)W + (size_t)(k0 + kr) * Nn + n0 + nc;
    #pragma unroll
    for (int j = 0; j < 16; ++j) tmp[j] = f2b(p[j]);
  } else {
    const u16* p = (const u16*)W + (size_t)(k0 + kr) * Nn + n0 + nc;
    #pragma unroll
    for (int j = 0; j < 16; ++j) tmp[j] = p[j];
  }
  #pragma unroll
  for (int j = 0; j < 16; ++j) Ts[kr][nc + j] = tmp[j];
  __syncthreads();
  const int nr = t >> 2, kc = (t & 3) * 16;
  u16 o[16];
  #pragma unroll
  for (int j = 0; j < 16; ++j) o[j] = Ts[kc + j][nr];
  u16* dst = WT + (size_t)(n0 + nr) * K + k0 + kc;
  *(uint4*)(dst) = *(uint4*)(o);
  *(uint4*)(dst + 8) = *(uint4*)(o + 8);
}

__global__ __launch_bounds__(256) void twT_k(const void* __restrict__ W, int K, int Nn,
                                             const int* __restrict__ flagp, u16* __restrict__ WT)
{
  __shared__ u16 Ts[64][80];
  twT_body(W, K, Nn, flagp[0], WT, blockIdx.x * 64, blockIdx.y * 64, threadIdx.x, Ts);
}

// Wpkv plain bf16 copy (original layout) body
__device__ __forceinline__ void wpkvb_body(const void* W0, int f32i, u16* Wb,
                                           int k0, int n0, int t)
{
  const int kr = t >> 2, nc = (t & 3) * 16;
  u16 tmp[16];
  if (f32i) {
    const float* p = (const float*)W0 + (size_t)(k0 + kr) * 1536 + n0 + nc;
    #pragma unroll
    for (int j = 0; j < 16; ++j) tmp[j] = f2b(p[j]);
  } else {
    const u16* p = (const u16*)W0 + (size_t)(k0 + kr) * 1536 + n0 + nc;
    #pragma unroll
    for (int j = 0; j < 16; ++j) tmp[j] = p[j];
  }
  u16* dst = Wb + (size_t)(k0 + kr) * 1536 + n0 + nc;
  *(uint4*)(dst) = *(uint4*)(tmp);
  *(uint4*)(dst + 8) = *(uint4*)(tmp + 8);
}

// merged: z=0 Wpkv^T, z=1 Wpq^T, z=2 Wproj^T, z=3 Wpkv plain bf16 (fallback path)
__global__ __launch_bounds__(256) void twT3_k(const void* __restrict__ W0, const void* __restrict__ W1,
                                              const void* __restrict__ W2, const int* __restrict__ flagp,
                                              u16* __restrict__ T0, u16* __restrict__ T1, u16* __restrict__ T2,
                                              u16* __restrict__ Wb)
{
  __shared__ u16 Ts[64][80];
  const int z = blockIdx.z;
  const int t = threadIdx.x;
  if (z == 3) {
    wpkvb_body(W0, flagp[0], Wb, blockIdx.x * 64, blockIdx.y * 64, t);
    return;
  }
  const void* W = (z == 0) ? W0 : (z == 1) ? W1 : W2;
  u16* WT = (z == 0) ? T0 : (z == 1) ? T1 : T2;
  const int Nn = (z == 0) ? 1536 : 768;
  if (blockIdx.y * 64 >= Nn) return;
  twT_body(W, 768, Nn, flagp[0], WT, blockIdx.x * 64, blockIdx.y * 64, t, Ts);
}

// ---------------- x -> bf16 body (8 elems per thread-index i) ----------------
__device__ __forceinline__ void xcvt_body(const void* x, int f32i, u16* xb, int i)
{
  if (f32i) {
    const float4* p = (const float4*)x + (size_t)i * 2;
    float4 f0 = p[0], f1 = p[1];
    u16 tmp[8] = { f2b(f0.x), f2b(f0.y), f2b(f0.z), f2b(f0.w),
                   f2b(f1.x), f2b(f1.y), f2b(f1.z), f2b(f1.w) };
    *(uint4*)(xb + (size_t)i * 8) = *(uint4*)tmp;
  } else {
    ((uint4*)xb)[i] = ((const uint4*)x)[i];
  }
}

__global__ __launch_bounds__(256) void xcvt_k(const void* __restrict__ x,
                                              const int* __restrict__ flagp, u16* __restrict__ xb)
{
  xcvt_body(x, flagp[0], xb, blockIdx.x * 256 + threadIdx.x);
}

// ---------------- fusedA: qselT (588) || twT WqkvT (432) || xcvt (2352) || twT3 (1152) ----
__global__ __launch_bounds__(256) void fusedA_k(const void* __restrict__ x, const void* __restrict__ Wqkv,
                                                const void* __restrict__ Wpq, const void* __restrict__ Wpkv,
                                                const void* __restrict__ Wproj,
                                                const int* __restrict__ flagp, float* __restrict__ qt,
                                                u16* __restrict__ WqkvT, u16* __restrict__ xb,
                                                u16* __restrict__ WpkvT, u16* __restrict__ WpqT,
                                                u16* __restrict__ WprojT, u16* __restrict__ Wpkvb)
{
  __shared__ float As[128 * 20];
  __shared__ float Bs[16 * 64];
  __shared__ u16 Ts[64][80];
  const int id = blockIdx.x;
  const int t = threadIdx.x;
  const int f32i = flagp[0];
  if (id < 588) {
    qsel_body(x, Wqkv, f32i, qt, (id % 49) * 128, (id / 49) * 64, t, As, Bs);
  } else if (id < 1020) {
    const int id2 = id - 588;
    twT_body(Wqkv, 768, 2304, f32i, WqkvT, (id2 % 12) * 64, (id2 / 12) * 64, t, Ts);
  } else if (id < 3372) {
    xcvt_body(x, f32i, xb, (id - 1020) * 256 + t);
  } else {
    const int id2 = id - 3372;          // 0..1151
    const int z = id2 / 288;
    const int rem = id2 - z * 288;
    const int bx = rem % 12, by = rem / 12;
    if (z == 3) {
      wpkvb_body(Wpkv, f32i, Wpkvb, bx * 64, by * 64, t);
    } else {
      const void* W = (z == 0) ? Wpkv : (z == 1) ? Wpq : Wproj;
      u16* WT = (z == 0) ? WpkvT : (z == 1) ? WpqT : WprojT;
      const int Nn = (z == 0) ? 1536 : 768;
      if (by * 64 < Nn)
        twT_body(W, 768, Nn, f32i, WT, bx * 64, by * 64, t, Ts);
    }
  }
}

// ---------------- shared GEMM core: global_load_lds staging + swizzled ds_read ----
struct GemmCore {
  const u16 *aP0, *aP1, *bP0, *bP1;
  u16 *lA0, *lA1, *lB0, *lB1;
  int roA[4], roB[4];
  int mw, nw, lr, lk;
};

__device__ __forceinline__ void gemm_core_init(GemmCore& gc, u16* As, u16* Bs,
    const u16* A16, const u16* B16, size_t aOff, size_t bOff,
    int m0, int n0, int lda, int ldb, int M, int t)
{
  const int lane = t & 63;
  const int w = t >> 6;
  gc.mw = (w >> 1) * 64;
  gc.nw = (w & 1) * 64;
  gc.lr = lane & 15;
  gc.lk = lane >> 4;
  const int c0 = w * 2, c1 = c0 + 1;
  const int rl = lane >> 2, sl = lane & 3;
  const int rowA0 = c0 * 16 + rl, rowA1 = c1 * 16 + rl;
  const int segA0 = (sl ^ ((rowA0 ^ (rowA0 >> 2)) & 3)) * 8;
  const int segA1 = (sl ^ ((rowA1 ^ (rowA1 >> 2)) & 3)) * 8;
  int ga0 = m0 + rowA0; if (ga0 >= M) ga0 = M - 1;
  int ga1 = m0 + rowA1; if (ga1 >= M) ga1 = M - 1;
  gc.aP0 = A16 + aOff + (size_t)ga0 * lda + segA0;
  gc.aP1 = A16 + aOff + (size_t)ga1 * lda + segA1;
  gc.bP0 = B16 + bOff + (size_t)(n0 + rowA0) * ldb + segA0;
  gc.bP1 = B16 + bOff + (size_t)(n0 + rowA1) * ldb + segA1;
  gc.lA0 = &As[c0 * 512]; gc.lA1 = &As[c1 * 512];
  gc.lB0 = &Bs[c0 * 512]; gc.lB1 = &Bs[c1 * 512];
  #pragma unroll
  for (int q = 0; q < 4; ++q) {
    const int ra = gc.mw + q * 16 + gc.lr;
    gc.roA[q] = ra * 32 + ((gc.lk ^ ((ra ^ (ra >> 2)) & 3)) * 8);
    const int rb = gc.nw + q * 16 + gc.lr;
    gc.roB[q] = rb * 32 + ((gc.lk ^ ((rb ^ (rb >> 2)) & 3)) * 8);
  }
}

__device__ __forceinline__ void gemm_core_loop(const GemmCore& gc, u16* As, u16* Bs,
                                               int K, f32x4 (&acc)[4][4])
{
  for (int k0 = 0; k0 < K; k0 += 32) {
    gll16(gc.aP0 + k0, gc.lA0);
    gll16(gc.aP1 + k0, gc.lA1);
    gll16(gc.bP0 + k0, gc.lB0);
    gll16(gc.bP1 + k0, gc.lB1);
    __syncthreads();
    bf16x8 af[4], bfv[4];
    #pragma unroll
    for (int mt = 0; mt < 4; ++mt) af[mt] = *(const bf16x8*)(&As[gc.roA[mt]]);
    #pragma unroll
    for (int nt = 0; nt < 4; ++nt) bfv[nt] = *(const bf16x8*)(&Bs[gc.roB[nt]]);
    #pragma unroll
    for (int mt = 0; mt < 4; ++mt)
      #pragma unroll
      for (int nt = 0; nt < 4; ++nt)
        acc[mt][nt] = __builtin_amdgcn_mfma_f32_16x16x32_bf16(af[mt], bfv[nt], acc[mt][nt], 0, 0, 0);
    __syncthreads();
  }
}

// MODE0 epilogue: qkv -> qb,kb,vb bf16 (bh,N,64), q/k scaled
__device__ __forceinline__ void mode0_epi(const f32x4 (&acc)[4][4], int m0, int n0,
                                          int mw, int nw, int lr, int lk,
                                          u16* ob0, u16* ob1, u16* ob2)
{
  #pragma unroll
  for (int mt = 0; mt < 4; ++mt) {
    #pragma unroll
    for (int nt = 0; nt < 4; ++nt) {
      #pragma unroll
      for (int r = 0; r < 4; ++r) {
        const int grow = m0 + mw + mt * 16 + lk * 4 + r;
        const int gcol = n0 + nw + nt * 16 + lr;
        float vv = acc[mt][nt][r];
        int b = (grow >= N_) ? 1 : 0;
        int n = grow - b * N_;
        int t3 = gcol / C_, cc = gcol - t3 * C_;
        int hh = cc >> 6, dd = cc & 63;
        size_t dst = (((size_t)(b * H_ + hh)) * N_ + n) * 64 + dd;
        if (t3 == 0) ob0[dst] = f2b(vv * SC_);
        else if (t3 == 1) ob1[dst] = f2b(vv * SC_);
        else ob2[dst] = f2b(vv);
      }
    }
  }
}

// ---------------- fusedB: landmarksR (192 blocks, 512thr) || gemm0 (882 blocks) ----------------
__global__ __launch_bounds__(512, 1) void fusedB_k(
    const float* __restrict__ qt, float* __restrict__ lm, u64* __restrict__ cand,
    const u16* __restrict__ xb, const u16* __restrict__ WqkvT,
    u16* __restrict__ qb, u16* __restrict__ kbuf, u16* __restrict__ vb)
{
  __shared__ double curD[64];
  __shared__ u64 redV[8];
  __shared__ int redI[8];
  __shared__ int sW;
  __shared__ u16 As[128 * 32];
  __shared__ u16 Bs[128 * 32];
  const int t = threadIdx.x;

  if (blockIdx.x >= 192) {
    const int gid = blockIdx.x - 192;
    const int m0 = (gid % 49) * 128;
    const int n0 = (gid / 49) * 128;
    if (t < 256) {
      f32x4 acc[4][4];
      #pragma unroll
      for (int i = 0; i < 4; ++i)
        #pragma unroll
        for (int j = 0; j < 4; ++j) acc[i][j] = (f32x4){0.f, 0.f, 0.f, 0.f};
      GemmCore gc;
      gemm_core_init(gc, As, Bs, xb, WqkvT, 0, 0, m0, n0, 768, 768, 6272, t);
      gemm_core_loop(gc, As, Bs, 768, acc);
      mode0_epi(acc, m0, n0, gc.mw, gc.nw, gc.lr, gc.lk, qb, kbuf, vb);
    } else {
      for (int i = 0; i < 24; ++i) { __syncthreads(); __syncthreads(); }
    }
    return;
  }

  // ---- landmarks role (R15/R17-proven body) ----
  const int bh = blockIdx.x % 24;
  const int kb = blockIdx.x / 24;
  const float* QT = qt + (size_t)bh * 64 * N_;   // [d][n]
  float* LM = lm + (size_t)bh * L_ * 64;
  u64* cd = cand + (size_t)bh * 16;
  const bool act = (t < RPB_);
  const int g = t >> 2, dc = t & 3, d0 = dc * 16;
  const int r0 = kb * RPB_;
  const int myRow = r0 + t;
  const float* base = QT + r0 + 4 * g;

  float4 qreg[16];
  #pragma unroll
  for (int i = 0; i < 16; ++i) qreg[i] = (float4){0.f, 0.f, 0.f, 0.f};
  if (act) {
    #pragma unroll
    for (int i = 0; i < 16; ++i) qreg[i] = *(const float4*)(base + (size_t)(d0 + i) * N_);
  }

  double inv_own = 0.0, ms_own = 0.0;
  if (act) {
    double s0 = 0.0, s1 = 0.0, s2 = 0.0, s3 = 0.0;
    #pragma unroll
    for (int i = 0; i < 16; ++i) {
      const float4 v = qreg[i];
      s0 += (double)v.x * (double)v.x; s1 += (double)v.y * (double)v.y;
      s2 += (double)v.z * (double)v.z; s3 += (double)v.w * (double)v.w;
    }
    s0 += __shfl_xor(s0, 1); s1 += __shfl_xor(s1, 1);
    s2 += __shfl_xor(s2, 1); s3 += __shfl_xor(s3, 1);
    s0 += __shfl_xor(s0, 2); s1 += __shfl_xor(s1, 2);
    s2 += __shfl_xor(s2, 2); s3 += __shfl_xor(s3, 2);
    const double sown = (dc == 0) ? s0 : (dc == 1) ? s1 : (dc == 2) ? s2 : s3;
    inv_own = 1.0 / fmax(sqrt(sown), 1e-12);
  }
  const int idx0 = tf_idx0(bh);
  if (act && myRow == idx0) ms_own = 10.0;

  if (t < 64) {
    const float vf = QT[(size_t)t * N_ + idx0];
    double v = (double)vf;
    double s = v * v;
    #pragma unroll
    for (int off = 32; off; off >>= 1) s += __shfl_xor(s, off);
    curD[t] = v / fmax(sqrt(s), 1e-12);
    if (kb == 0) LM[t] = vf;
  }
  __syncthreads();

  for (int step = 1; step < 128; ++step) {
    u64 bV = d2u(1e30); int bI = 0x7fffffff;
    if (act) {
      double a0 = 0.0, a1 = 0.0, a2 = 0.0, a3 = 0.0;
      #pragma unroll
      for (int i = 0; i < 16; ++i) {
        const float4 v = qreg[i];
        const double c = curD[d0 + i];
        a0 += (double)v.x * c; a1 += (double)v.y * c;
        a2 += (double)v.z * c; a3 += (double)v.w * c;
      }
      a0 += __shfl_xor(a0, 1); a1 += __shfl_xor(a1, 1);
      a2 += __shfl_xor(a2, 1); a3 += __shfl_xor(a3, 1);
      a0 += __shfl_xor(a0, 2); a1 += __shfl_xor(a1, 2);
      a2 += __shfl_xor(a2, 2); a3 += __shfl_xor(a3, 2);
      const double aown = (dc == 0) ? a0 : (dc == 1) ? a1 : (dc == 2) ? a2 : a3;
      ms_own = fmax(ms_own, fabs(aown * inv_own));
      bV = d2u(ms_own); bI = myRow;
    }
    #pragma unroll
    for (int off = 32; off; off >>= 1) {
      const u64 ov = __shfl_xor(bV, off);
      const int oi = __shfl_xor(bI, off);
      if (ov < bV || (ov == bV && oi < bI)) { bV = ov; bI = oi; }
    }
    if ((t & 63) == 0) { redV[t >> 6] = bV; redI[t >> 6] = bI; }
    __syncthreads();
    const int par = step & 1;
    if (t == 0) {
      u64 v = redV[0]; int ix = redI[0];
      #pragma unroll
      for (int w2 = 1; w2 < 8; ++w2)
        if (redV[w2] < v || (redV[w2] == v && redI[w2] < ix)) { v = redV[w2]; ix = redI[w2]; }
      const u64 pk = (v & ~((1ull << 19) - 1ull)) | ((u64)(u32)(step & 127) << 12) | (u64)(u32)ix;
      __hip_atomic_store(&cd[par * KB_ + kb], pk, __ATOMIC_RELAXED, __HIP_MEMORY_SCOPE_AGENT);
    }
    if (t < 64) {
      u64 pv = ~0ull;
      int ok = 1;
      for (;;) {
        if (t < KB_) {
          pv = __hip_atomic_load(&cd[par * KB_ + t], __ATOMIC_RELAXED, __HIP_MEMORY_SCOPE_AGENT);
          ok = ((int)((pv >> 12) & 127u) == step) ? 1 : 0;
        }
        if (__all(ok)) break;
        __builtin_amdgcn_s_sleep(1);
      }
      u64 m = (t < KB_) ? pv : ~0ull;
      #pragma unroll
      for (int off = 1; off < KB_; off <<= 1) {
        const u64 o = __shfl_xor(m, off);
        if (o < m) m = o;
      }
      if (t == 0) sW = (int)(m & 0xFFFu);
    }
    __syncthreads();
    const int w = sW;
    if (act && myRow == w) ms_own = 10.0;
    if (t < 64) {
      const float vf = QT[(size_t)t * N_ + w];
      double v = (double)vf;
      double s = v * v;
      #pragma unroll
      for (int off = 32; off; off >>= 1) s += __shfl_xor(s, off);
      curD[t] = v / fmax(sqrt(s), 1e-12);
      if (kb == 0) LM[(size_t)step * 64 + t] = vf;
    }
    __syncthreads();
  }
}

// ---------------- k1 body: kernel_1 = softmax_l(q . lm^T), bf16 out ----------------
__device__ __forceinline__ void k1_body(const u16* qb, const float* lm, u16* k1,
                                        int bh, int r0, int t, char* smem)
{
  float (*qT)[65] = (float(*)[65])smem;                       // 16640 B
  float* lmS = (float*)(smem + 16640);                        // 32768 B
  float (*redA)[64] = (float(*)[64])(smem + 16640 + 32768);   // 1024 B
  float* redB = (float*)(smem + 16640 + 32768 + 1024);        // 256 B
  const u16* Q = qb + ((size_t)bh * N_ + r0) * 64;
  const float* Lm = lm + (size_t)bh * L_ * 64;
  for (int u = t; u < 2048; u += 256) ((float4*)lmS)[u] = ((const float4*)Lm)[u];
  for (int u = t; u < 512; u += 256) {
    int row = u >> 3, j0 = (u & 7) * 8;
    uint4 pk = *(const uint4*)(Q + (size_t)row * 64 + j0);
    const u16* pu = (const u16*)&pk;
    #pragma unroll
    for (int jj = 0; jj < 8; ++jj) qT[j0 + jj][row] = b2f(pu[jj]);
  }
  __syncthreads();
  const int row = t & 63, ch = t >> 6;
  float qr[64];
  #pragma unroll
  for (int j = 0; j < 64; ++j) qr[j] = qT[j][row];
  float s[32];
  for (int li = 0; li < 32; ++li) {
    const float* lp = lmS + (ch * 32 + li) * 64;
    float a = 0.f;
    #pragma unroll
    for (int j = 0; j < 64; ++j) a += lp[j] * qr[j];
    s[li] = a;
  }
  float mx = -1e30f;
  for (int li = 0; li < 32; ++li) mx = fmaxf(mx, s[li]);
  redA[ch][row] = mx;
  __syncthreads();
  if (t < 64) redB[t] = fmaxf(fmaxf(redA[0][t], redA[1][t]), fmaxf(redA[2][t], redA[3][t]));
  __syncthreads();
  mx = redB[row];
  float sum = 0.f;
  for (int li = 0; li < 32; ++li) { float e = __expf(s[li] - mx); s[li] = e; sum += e; }
  __syncthreads();
  redA[ch][row] = sum;
  __syncthreads();
  if (t < 64) redB[t] = 1.0f / (redA[0][t] + redA[1][t] + redA[2][t] + redA[3][t]);
  __syncthreads();
  const float inv = redB[row];
  u16* out = k1 + ((size_t)bh * N_ + r0 + row) * 128 + ch * 32;
  for (int li = 0; li < 32; ++li) out[li] = f2b(s[li] * inv);
}

// ---------------- k2x1 body: kernel_2 per frame + x1 = kernel_2 @ v (transposed out) ----
__device__ __forceinline__ void k2x1_body(const float* lm, const u16* kb, const u16* vb,
                                          u16* x1, int bh, int f, int t, char* smem)
{
  u16* kS = (u16*)smem;                                     // 25088 B
  u16* vS = (u16*)(smem + 25088);                           // 25088 B
  float (*redM)[128] = (float(*)[128])(smem + 50176);       // 1024 B
  float (*redS)[128] = (float(*)[128])(smem + 51200);       // 1024 B
  const u16* Kf = kb + ((size_t)bh * N_ + f * P_) * 64;
  const u16* Vf = vb + ((size_t)bh * N_ + f * P_) * 64;
  for (int u = t; u < 1568; u += 256) {
    ((uint4*)kS)[u] = ((const uint4*)Kf)[u];
    ((uint4*)vS)[u] = ((const uint4*)Vf)[u];
  }
  __syncthreads();
  const int l = t & 127, half = t >> 7;
  const float* lp = lm + ((size_t)bh * L_ + l) * 64;
  float lr[64];
  #pragma unroll
  for (int j = 0; j < 64; ++j) lr[j] = lp[j];

  const int p0 = half * 98, p1 = p0 + 98;
  float mx = -1e30f;
  for (int p = p0; p < p1; ++p) {
    const uint4* kp = (const uint4*)(kS + p * 64);
    float s = 0.f;
    #pragma unroll
    for (int q4 = 0; q4 < 8; ++q4) {
      uint4 pk = kp[q4];
      const u32* pu = (const u32*)&pk;
      #pragma unroll
      for (int j2 = 0; j2 < 4; ++j2) {
        u32 u = pu[j2];
        s += lr[q4 * 8 + j2 * 2] * lo16f(u) + lr[q4 * 8 + j2 * 2 + 1] * hi16f(u);
      }
    }
    mx = fmaxf(mx, s);
  }
  redM[half][l] = mx;
  __syncthreads();
  mx = fmaxf(redM[0][l], redM[1][l]);

  float sm = 0.f;
  for (int p = p0; p < p1; ++p) {
    const uint4* kp = (const uint4*)(kS + p * 64);
    float s = 0.f;
    #pragma unroll
    for (int q4 = 0; q4 < 8; ++q4) {
      uint4 pk = kp[q4];
      const u32* pu = (const u32*)&pk;
      #pragma unroll
      for (int j2 = 0; j2 < 4; ++j2) {
        u32 u = pu[j2];
        s += lr[q4 * 8 + j2 * 2] * lo16f(u) + lr[q4 * 8 + j2 * 2 + 1] * hi16f(u);
      }
    }
    sm += __expf(s - mx);
  }
  redS[half][l] = sm;
  __syncthreads();
  const float inv = 1.0f / (redS[0][l] + redS[1][l]);

  const int dd0 = half * 32;
  float acc[32];
  #pragma unroll
  for (int u = 0; u < 32; ++u) acc[u] = 0.f;
  for (int p = 0; p < P_; ++p) {
    const uint4* kp = (const uint4*)(kS + p * 64);
    float s = 0.f;
    #pragma unroll
    for (int q4 = 0; q4 < 8; ++q4) {
      uint4 pk = kp[q4];
      const u32* pu = (const u32*)&pk;
      #pragma unroll
      for (int j2 = 0; j2 < 4; ++j2) {
        u32 u = pu[j2];
        s += lr[q4 * 8 + j2 * 2] * lo16f(u) + lr[q4 * 8 + j2 * 2 + 1] * hi16f(u);
      }
    }
    const float e = __expf(s - mx);
    const uint4* vp = (const uint4*)(vS + p * 64 + dd0);
    #pragma unroll
    for (int q4 = 0; q4 < 4; ++q4) {
      uint4 pv = vp[q4];
      const u32* pu = (const u32*)&pv;
      #pragma unroll
      for (int j2 = 0; j2 < 4; ++j2) {
        u32 u = pu[j2];
        acc[q4 * 8 + j2 * 2]     += e * lo16f(u);
        acc[q4 * 8 + j2 * 2 + 1] += e * hi16f(u);
      }
    }
  }
  u16* outT = x1 + (size_t)bh * (1024 * 128) + (size_t)(f * 64 + dd0) * 128 + l;
  for (int u = 0; u < 32; ++u) outT[(size_t)u * 128] = f2b(acc[u] * inv);
}

// ---------------- fusedC: k2x1 (384 blocks) || k1 (1176 blocks) ----------------
__global__ __launch_bounds__(256) void fusedC_k(const u16* __restrict__ qb,
                                                const float* __restrict__ lm,
                                                const u16* __restrict__ kbuf,
                                                const u16* __restrict__ vb,
                                                u16* __restrict__ k1b, u16* __restrict__ x1b)
{
  __shared__ __align__(16) char smem[52224];
  const int id = blockIdx.x;
  const int t = threadIdx.x;
  if (id < 384) {
    k2x1_body(lm, kbuf, vb, x1b, id % 24, id / 24, t, smem);
  } else {
    const int id2 = id - 384;
    k1_body(qb, lm, k1b, id2 / 49, (id2 % 49) * 64, t, smem);
  }
}

// ---------------- generic 128x128 bf16 MFMA GEMM, per-mode epilogues ----
// MODE 0: qkv->qb,kb,vb | 1: xoc+xdc | 3: q2b | 4: final out | 5: g | 6: ob part
template <int MODE>
__global__ __launch_bounds__(256) void gemm_k(
    const void* __restrict__ Ap, const void* __restrict__ Bp,
    int M, int K, int lda, int ldb, int n0c, int cn, const int* __restrict__ flagp,
    float* __restrict__ of0, u16* __restrict__ ob0, u16* __restrict__ ob1, u16* __restrict__ ob2,
    const void* __restrict__ biasRaw, void* __restrict__ outRaw)
{
  __shared__ u16 As[128 * 32];
  __shared__ u16 Bs[128 * 32];
  const int t = threadIdx.x;
  const int m0 = blockIdx.x * 128;
  const int n0 = blockIdx.y * 128;
  const int rf = (MODE == 4) ? flagp[0] : 0;

  size_t aOff = 0, bOff = 0;
  if constexpr (MODE == 1) {
    const int bh = blockIdx.z;
    aOff = (size_t)bh * ((size_t)N_ * 128) + (size_t)n0c * 128;
    bOff = (size_t)bh * (1024 * 128);
  }
  if constexpr (MODE == 5) {
    const int h = blockIdx.z;
    aOff = (size_t)h * (2 * cn) * 64;
    bOff = (size_t)h * 64;
  }
  if constexpr (MODE == 6) {
    const int h = blockIdx.z;
    aOff = (size_t)h * (2 * cn) * 768;
    bOff = (size_t)(768 + h * 64) * 768;
  }
  f32x4 acc[4][4];
  #pragma unroll
  for (int i = 0; i < 4; ++i)
    #pragma unroll
    for (int j = 0; j < 4; ++j) acc[i][j] = (f32x4){0.f, 0.f, 0.f, 0.f};

  GemmCore gc;
  gemm_core_init(gc, As, Bs, (const u16*)Ap, (const u16*)Bp, aOff, bOff, m0, n0, lda, ldb, M, t);
  gemm_core_loop(gc, As, Bs, K, acc);

  const int lr = gc.lr, lk = gc.lk, mw = gc.mw, nw = gc.nw;
  if constexpr (MODE == 0) {
    mode0_epi(acc, m0, n0, mw, nw, lr, lk, ob0, ob1, ob2);
    return;
  }
  #pragma unroll
  for (int mt = 0; mt < 4; ++mt) {
    #pragma unroll
    for (int nt = 0; nt < 4; ++nt) {
      #pragma unroll
      for (int r = 0; r < 4; ++r) {
        const int grow = m0 + mw + mt * 16 + lk * 4 + r;
        const int gcol = n0 + nw + nt * 16 + lr;
        if (grow >= M) continue;
        float vv = acc[mt][nt][r];
        if constexpr (MODE == 1) {           // xoc (B,cn,F,C) bf16 + xdiag side-write
          const int bh = blockIdx.z;
          int b = bh / H_, hh = bh - b * H_;
          int f = gcol >> 6, dd = gcol & 63;
          u16 wv = f2b(vv);
          ob0[(((size_t)(b * cn + grow)) * F_ + f) * C_ + hh * 64 + dd] = wv;
          int n = n0c + grow;
          if (f == n / P_) ob1[((size_t)(b * cn + grow)) * C_ + hh * 64 + dd] = wv;
        } else if constexpr (MODE == 3) {    // q2b [h][2cn][64] bf16, * 0.125
          int hh = gcol >> 6, dd = gcol & 63;
          ob0[((size_t)hh * (2 * cn) + grow) * 64 + dd] = f2b(vv * 0.125f);
        } else if constexpr (MODE == 5) {    // g [h][2cn][768] bf16
          ob0[((size_t)blockIdx.z * (2 * cn) + grow) * 768 + gcol] = f2b(vv);
        } else if constexpr (MODE == 6) {    // ob part: out_h = wc_h @ Wpkv_v_h
          if (gcol < 64) {
            int b2 = (grow >= cn) ? 1 : 0;
            int ln = grow - b2 * cn;
            ob0[((size_t)(b2 * N_ + n0c + ln)) * 768 + blockIdx.z * 64 + gcol] = f2b(vv);
          }
        } else {                             // MODE 4: out = o@W_proj + b_proj
          float bvad = rf ? ((const float*)biasRaw)[gcol] : b2f(((const u16*)biasRaw)[gcol]);
          float ov = vv + bvad;
          if (rf) ((float*)outRaw)[(size_t)grow * C_ + gcol] = ov;
          else    ((u16*)outRaw)[(size_t)grow * C_ + gcol] = f2b(ov);
        }
      }
    }
  }
}

// ---------------- reassociated attention: logits = g.Xo, softmax, w = attn.Xo ----------------
__global__ __launch_bounds__(256) void attn2_k(const u16* __restrict__ xoc,
                                               const u16* __restrict__ g,
                                               int n0c, int cn, const int* __restrict__ flagp,
                                               void* __restrict__ outRaw, u16* __restrict__ wc)
{
  __shared__ float aS[12][16];
  const int t = threadIdx.x;
  const int m = blockIdx.x;
  const int b = (m >= cn) ? 1 : 0;
  const int ln = m - b * cn;
  const int n = n0c + ln;
  const int f32o = flagp[0];
  const u16* Xo = xoc + ((size_t)(b * cn + ln) * 16) * 768;
  const size_t hstr = (size_t)(2 * cn) * 768;

  if (t < 192) {
    const int h = t >> 4, f = t & 15;
    const uint4* xp = (const uint4*)(Xo + (size_t)f * 768);
    const uint4* gp = (const uint4*)(g + (size_t)h * hstr + (size_t)m * 768);
    float lg = 0.f;
    #pragma unroll 4
    for (int q = 0; q < 96; ++q) {
      uint4 xv = xp[q], gv = gp[q];
      const u32* xu = (const u32*)&xv;
      const u32* gu = (const u32*)&gv;
      #pragma unroll
      for (int j = 0; j < 4; ++j)
        lg += lo16f(xu[j]) * lo16f(gu[j]) + hi16f(xu[j]) * hi16f(gu[j]);
    }
    float mx = lg;
    mx = fmaxf(mx, __shfl_xor(mx, 1));
    mx = fmaxf(mx, __shfl_xor(mx, 2));
    mx = fmaxf(mx, __shfl_xor(mx, 4));
    mx = fmaxf(mx, __shfl_xor(mx, 8));
    float e = __expf(lg - mx);
    float sm = e;
    sm += __shfl_xor(sm, 1);
    sm += __shfl_xor(sm, 2);
    sm += __shfl_xor(sm, 4);
    sm += __shfl_xor(sm, 8);
    const float a = e / sm;
    const size_t abase = ((size_t)(b * H_ + h) * N_ + n) * F_ + f;
    if (f32o) ((float*)outRaw)[OUTPART_ + abase] = a;
    else      ((u16*)outRaw)[OUTPART_ + abase] = f2b(a);
    aS[h][f] = a;
  }
  __syncthreads();
  if (t < 192) {
    const int cg = t >> 1, sh = t & 1;
    const int c0 = cg * 8;
    float acc[6][8];
    #pragma unroll
    for (int j = 0; j < 6; ++j)
      #pragma unroll
      for (int k = 0; k < 8; ++k) acc[j][k] = 0.f;
    for (int f = 0; f < 16; ++f) {
      uint4 xv = *(const uint4*)(Xo + (size_t)f * 768 + c0);
      const u32* xu = (const u32*)&xv;
      float xf[8];
      #pragma unroll
      for (int j = 0; j < 4; ++j) { xf[2 * j] = lo16f(xu[j]); xf[2 * j + 1] = hi16f(xu[j]); }
      #pragma unroll
      for (int j = 0; j < 6; ++j) {
        const float a = aS[sh * 6 + j][f];
        #pragma unroll
        for (int k = 0; k < 8; ++k) acc[j][k] += a * xf[k];
      }
    }
    #pragma unroll
    for (int j = 0; j < 6; ++j) {
      u16 pk[8];
      #pragma unroll
      for (int k = 0; k < 8; ++k) pk[k] = f2b(acc[j][k]);
      *(uint4*)(wc + (size_t)(sh * 6 + j) * hstr + (size_t)m * 768 + c0) = *(uint4*)pk;
    }
  }
}

extern "C" void kernel_launch(void* const* d_in, const int* in_sizes, int n_in,
                              void* d_out, int out_size, void* d_ws, size_t ws_size,
                              hipStream_t stream)
{
  (void)in_sizes; (void)n_in; (void)out_size;
  const void* x     = d_in[0];
  const void* Wqkv  = d_in[1];
  const void* Wpq   = d_in[2];
  const void* Wpkv  = d_in[3];
  const void* Wproj = d_in[4];
  const void* bproj = d_in[5];

  char* ws = (char*)d_ws;
  size_t off = 0;
  auto alloc = [&](size_t bytes) { void* p = ws + off; off += (bytes + 255) & ~(size_t)255; return p; };
  // ---- fixed region (live across the chunk loop) ----
  int*  flagp  = (int*)alloc(256);
  u16*  WpkvT  = (u16*)alloc(2359296);   // [1536][768] bf16
  u16*  WpqT   = (u16*)alloc(1179648);   // [768][768]
  u16*  WprojT = (u16*)alloc(1179648);   // [768][768]
  u16*  Wpkvb  = (u16*)alloc(2359296);   // [768][1536] bf16, original layout
  float* lm    = (float*)alloc(786432);  // (bh,128,64) f32
  u16*  x1b    = (u16*)alloc(6291456);   // (bh,1024,128) bf16 TRANSPOSED
  u16*  k1b    = (u16*)alloc(19267584);  // (bh,N,128) bf16
  const size_t sc0 = off;                // scratch start (~33.4 MB)

  // ob (B,N,C bf16, 9.63MB) lives at the END of ws — time-shares the dead
  // qb/kbuf/vb tail; chunk region = [sc0, obOff).
  if (ws_size < sc0 + 9633792 + 1024) return;
  const size_t obOff = (ws_size - 9633792) & ~(size_t)255;
  u16* ob = (u16*)(ws + obOff);

  // fused layout: [qt+cand][WqkvT+xb][qb+kbuf+vb] concurrently live
  const size_t r1 = sc0;
  const size_t r2 = r1 + 19267584 + 3072;
  const size_t r3 = r2 + 3538944 + 9633792;
  const size_t bigNeed = r3 + 3 * (size_t)9633792 + 256;
  const bool fused = (bigNeed <= ws_size);

  float* qt;  u64* cand;  u16 *WqkvT, *xb, *qb, *kbuf, *vb;
  if (fused) {
    qt    = (float*)(ws + r1);
    cand  = (u64*)(ws + r1 + 19267584);
    WqkvT = (u16*)(ws + r2);
    xb    = WqkvT + 1769472;             // 3538944 B
    qb    = (u16*)(ws + r3);
    kbuf  = qb + 4816896;
    vb    = kbuf + 4816896;
  } else {
    // sequential fallback: overlays
    qt    = (float*)(ws + sc0);
    cand  = (u64*)(ws + sc0 + 19267584);
    WqkvT = (u16*)(ws + sc0);
    xb    = (u16*)(ws + sc0 + 3538944);
    qb    = (u16*)(ws + sc0 + 13172736);
    kbuf  = qb + 4816896;
    vb    = kbuf + 4816896;
    if (sc0 + 42074112 + 1024 > ws_size) return;
  }

  int Nc = 0;
  {
    const int cands[6] = {1568, 784, 448, 392, 224, 196};
    for (int i = 0; i < 6; ++i) {
      if (sc0 + (size_t)92160 * cands[i] <= obOff) { Nc = cands[i]; break; }
    }
  }
  if (Nc == 0) return;
  const int nchunks = N_ / Nc;
  u16* xoc = (u16*)(ws + sc0);            // (B,Nc,F,C) bf16
  u16* xdc = xoc + (size_t)24576 * Nc;    // (B,Nc,C) bf16
  u16* q2b = xdc + (size_t)1536 * Nc;     // [h][2Nc][64] bf16
  u16* gbf = q2b + (size_t)1536 * Nc;     // [h][2Nc][768] bf16; wc overwrites in place

  detect_k<<<1, 64, 0, stream>>>((const u32*)Wqkv, flagp);
  zcnt_k<<<1, 512, 0, stream>>>(cand);

  if (fused) {
    // qselT || twT(WqkvT) || xcvt || twT3 weight prep (all independent)
    fusedA_k<<<4524, 256, 0, stream>>>(x, Wqkv, Wpq, Wpkv, Wproj, flagp, qt,
                                       WqkvT, xb, WpkvT, WpqT, WprojT, Wpkvb);
    // landmarks || gemm0 (qkv projection)
    fusedB_k<<<1074, 512, 0, stream>>>(qt, lm, cand, xb, WqkvT, qb, kbuf, vb);
  } else {
    twT3_k<<<dim3(12, 24, 4), 256, 0, stream>>>(Wpkv, Wpq, Wproj, flagp,
                                                WpkvT, WpqT, WprojT, Wpkvb);
    qselT_k<<<dim3(49, 12), 256, 0, stream>>>(x, Wqkv, flagp, qt);
    fusedB_k<<<192, 512, 0, stream>>>(qt, lm, cand, xb, WqkvT, qb, kbuf, vb);  // landmarks only
    twT_k<<<dim3(12, 36), 256, 0, stream>>>(Wqkv, 768, 2304, flagp, WqkvT);
    xcvt_k<<<2352, 256, 0, stream>>>(x, flagp, xb);
    gemm_k<0><<<dim3(49, 18, 1), 256, 0, stream>>>(xb, WqkvT, 6272, 768, 768, 768, 0, 0, flagp,
                                                   nullptr, qb, kbuf, vb, nullptr, nullptr);
  }

  // k2x1 || k1 (independent inputs)
  fusedC_k<<<1560, 256, 0, stream>>>(qb, lm, kbuf, vb, k1b, x1b);

  const int gx = (2 * Nc + 127) / 128;
  for (int c = 0; c < nchunks; ++c) {
    const int n0c = c * Nc;
    // xo = k1 @ x1 (+ xdiag side-write)
    gemm_k<1><<<dim3((Nc + 127) / 128, 8, 24), 256, 0, stream>>>(
        k1b, x1b, Nc, 128, 128, 128, n0c, Nc, flagp, nullptr, xoc, xdc, nullptr, nullptr, nullptr);
    // q2b = bf16(xdiag @ Wpq * 0.125), [h][2Nc][64]
    gemm_k<3><<<dim3(gx, 6, 1), 256, 0, stream>>>(
        xdc, WpqT, 2 * Nc, 768, 768, 768, n0c, Nc, flagp, nullptr, q2b, nullptr, nullptr, nullptr, nullptr);
    // g = bf16(q2b @ Wpkv_k^T), K=64, per-head
    gemm_k<5><<<dim3(gx, 6, 12), 256, 0, stream>>>(
        q2b, Wpkvb, 2 * Nc, 64, 64, 1536, n0c, Nc, flagp, nullptr, gbf, nullptr, nullptr, nullptr, nullptr);
    // logits = g.Xo -> softmax -> attn out + w = attn.Xo (wc in place of g)
    attn2_k<<<dim3(2 * Nc), 256, 0, stream>>>(xoc, gbf, n0c, Nc, flagp, d_out, gbf);
    // ob_h = wc_h @ Wpkv_v_h (N=64 masked)
    gemm_k<6><<<dim3(gx, 1, 12), 256, 0, stream>>>(
        gbf, WpkvT, 2 * Nc, 768, 768, 768, n0c, Nc, flagp, nullptr, ob, nullptr, nullptr, nullptr, nullptr);
  }
  // out = o @ W_proj + b_proj
  gemm_k<4><<<dim3(49, 6, 1), 256, 0, stream>>>(ob, WprojT, 6272, 768, 768, 768, 0, 0, flagp,
                                                nullptr, nullptr, nullptr, nullptr, bproj, d_out);
}